// Round 8
// baseline (352.822 us; speedup 1.0000x reference)
//
#include <hip/hip_runtime.h>
#include <hip/hip_bf16.h>

typedef __bf16          bf16x8 __attribute__((ext_vector_type(8)));
typedef float           f32x4  __attribute__((ext_vector_type(4)));
typedef unsigned int    u32x2  __attribute__((ext_vector_type(2)));
typedef unsigned int    u32x4v __attribute__((ext_vector_type(4)));

// d_ws layout (bytes)
#define QKW_OFF  0           // 512*256 bf16                        (262144)
#define VW_OFF   262144      // 1024*256 bf16                       (524288)
#define PJW_OFF  786432      // 256*1024 bf16                       (524288)
#define BIAS_OFF 1310720     // [16 win][8 h][16 chunk][64 lane][4 r] f32 (2097152)
#define XT_OFF   70516736    // [64 b][16 win][49 px][256 c] bf16   (25690112)

#define MFMA(a,b,c) __builtin_amdgcn_mfma_f32_16x16x32_bf16((a),(b),(c),0,0,0)
#define ZERO4 ((f32x4){0.f,0.f,0.f,0.f})
#define CBAR() asm volatile("" ::: "memory")

// LDS map (76288 B):
//   [0, 25088)        sXN [49 px][256 c] bf16, row 512 B, swz ^((row&7)<<4)
//   [25088, 76288)    8 regions of 6400 B (50*128, 128-aligned bases):
//                     per-wave scratch during attention (q/k -> P -> va),
//                     then out[49 q][64 ch] row 128 B; then idle-v [49 px][64 ch].
#define SXN_AT(row, byte)      ((((row)*512 + (byte))) ^ ((((row)&7))<<4))
#define RGB(j)                 (25088 + (j)*6400)
#define RG_AT(base, row, byte) (((base) + (row)*128 + (byte)) ^ (((row)&7)<<4))

static __device__ __forceinline__ unsigned cvtpk(float lo, float hi){
  unsigned r;
  asm("v_cvt_pk_bf16_f32 %0, %1, %2" : "=v"(r) : "v"(lo), "v"(hi));
  return r;
}
static __device__ __forceinline__ unsigned short f2bu(float f) {
  unsigned u = __builtin_bit_cast(unsigned, f);
  return (unsigned short)((u + 0x7FFFu + ((u >> 16) & 1u)) >> 16);
}
static __device__ __forceinline__ float gelu_f(float v){
  // v * sigmoid(1.5957691*v*(1+0.044715 v^2)) == tanh-form gelu, |err| < ~1e-3
  return v / (1.f + __expf(-1.5957691216057308f*v*(1.f + 0.044715f*v*v)));
}

// ---------------- prep (single launch): pre-LN/window transform + weights + bias ----------------
// blocks [0,1600): pre-LN + NCHW->xt window transform (chunk = blk%25, b = blk/25)
// blocks [1600,4160): weight fp32->bf16 convert
// blocks [4160,4288): bias table build
__global__ __launch_bounds__(256)
void emo_prep(const float* __restrict__ x, const float* __restrict__ pre_w,
              const float* __restrict__ pre_b,
              const float* __restrict__ qk_w, const float* __restrict__ v_w,
              const float* __restrict__ proj_w, const float* __restrict__ rpb,
              unsigned short* __restrict__ xt,
              unsigned short* __restrict__ w16, float* __restrict__ bx) {
  const int blk = blockIdx.x;
  const int tid = threadIdx.x;
  if (blk >= 1600) {
    if (blk < 4160) {          // ---- weight convert ----
      int i = (blk - 1600) * 256 + tid;
      if (i >= 655360) return;
      float v;
      if (i < 131072)      v = qk_w[i];
      else if (i < 393216) v = v_w[i - 131072];
      else                 v = proj_w[i - 393216];
      unsigned u = __builtin_bit_cast(unsigned, v);
      w16[i] = (unsigned short)((u + 0x7FFFu + ((u >> 16) & 1u)) >> 16);
    } else {                   // ---- bias table ----
      const int wh = blk - 4160;          // win*8 + h
      const int win = wh >> 3, h = wh & 7;
      for (int e = tid; e < 4096; e += 256) {
        const int chunk = e >> 8, lane = (e >> 2) & 63, r = e & 3;
        const int mt = chunk >> 2, nt = chunk & 3;
        const int m = mt*16 + (lane >> 4)*4 + r;   // query pixel
        const int n = nt*16 + (lane & 15);         // key pixel
        float v;
        if (n >= 49)      v = -1e30f;              // softmax mask over key dim
        else if (m >= 49) v = 0.f;
        else {
          const int dI = m/7 - n/7 + 6;
          const int dJ = m%7 - n%7 + 6;
          v = rpb[(win*169 + dI*13 + dJ)*8 + h];
        }
        bx[wh*4096 + e] = v;
      }
    }
    return;
  }
  // ---- pre-LN + window transform ----
  __shared__ float lv[32*257];     // 32896 B
  __shared__ float ps1[8][32];
  __shared__ float ps2[8][32];
  const int lane = tid & 63, wv = tid >> 6;
  const int l32 = lane & 31, hp = lane >> 5;
  const int chunk = blk % 25, b = blk / 25;
  const int s = chunk*32 + l32;            // spatial index h*28+w
  const bool ok = s < 784;
  const float* xb = x + (size_t)b*200704;  // 256*784
  float s1 = 0.f, s2 = 0.f;
  const int c0 = wv*64 + hp*32;
  for (int ci = 0; ci < 32; ++ci) {
    const int c = c0 + ci;
    const float v = ok ? xb[c*784 + s] : 0.f;
    lv[l32*257 + c] = v;
    s1 += v; s2 += v*v;
  }
  ps1[wv*2 + hp][l32] = s1;
  ps2[wv*2 + hp][l32] = s2;
  __syncthreads();
  const int px = tid & 31, j = tid >> 5;
  const int sp = chunk*32 + px;
  if (sp < 784) {
    float t1 = 0.f, t2 = 0.f;
    #pragma unroll
    for (int k = 0; k < 8; ++k) { t1 += ps1[k][px]; t2 += ps2[k][px]; }
    const float mu = t1*(1.f/256.f);
    const float rs = rsqrtf(t2*(1.f/256.f) - mu*mu + 1e-5f);
    const int h = sp/28, w = sp - h*28;
    const int win = (h & 3)*4 + (w & 3);         // n1*4 + n2
    const int wpx = (h >> 2)*7 + (w >> 2);       // ph*7 + pw
    unsigned short* row = xt + (((size_t)b*16 + win)*49 + wpx)*256 + j*32;
    #pragma unroll
    for (int g = 0; g < 4; ++g) {
      float gg[8];
      #pragma unroll
      for (int i2 = 0; i2 < 8; ++i2) {
        const int c = j*32 + g*8 + i2;
        gg[i2] = (lv[px*257 + c] - mu)*rs*pre_w[c] + pre_b[c];
      }
      u32x4v pk = { cvtpk(gg[0],gg[1]), cvtpk(gg[2],gg[3]), cvtpk(gg[4],gg[5]), cvtpk(gg[6],gg[7]) };
      *(u32x4v*)(row + g*8) = pk;
    }
  }
}

// ---------------- main fused kernel (R7 structure + idle-v via regions) ----------------
// Input path: coalesced xt read. Output: fused residual+roll store (needs R0's
// batch-grouped mapping for L2 write-merging of interleaved window lines — R6 lesson).
// Idle-v now computed directly into each wave's region (D[ch][px] orientation),
// after the attn-half proj loop consumes the regions: removes the SC overlay,
// 2 of 4 idle-phase barriers, and 64 KB of LDS round trips per block.
__global__ __launch_bounds__(512, 4)
void emo_main(const float* __restrict__ x,
              const float* __restrict__ qk_b,  const float* __restrict__ v_b,
              const float* __restrict__ post_w,const float* __restrict__ post_b,
              const float* __restrict__ proj_b,
              const char*  __restrict__ wsc,
              float* __restrict__ out)
{
  extern __shared__ char smem[];
  const int tid  = threadIdx.x;
  const int lane = tid & 63;
  const int l16  = lane & 15;
  const int lk   = lane >> 4;
  const int wv   = tid >> 6;                 // wave = head
  const int bid  = blockIdx.x;
  const int Bi   = (bid & 7) * 8 + (bid >> 7);   // XCD swizzle (bijective, R0 form)
  const int win  = (bid >> 3) & 15;
  const int n1   = win >> 2, n2 = win & 3;
  const size_t xbase = (size_t)Bi * (256*784);
  const int SCR  = RGB(wv);                  // per-wave scratch base

  // ---- prefetch qk weights for kt=0 (independent of LDS; hides L2 latency at barrier) ----
  bf16x8 awq0[2], awk0[2];
  #pragma unroll
  for (int mt = 0; mt < 2; ++mt) {
    awq0[mt] = *(const bf16x8*)(wsc + QKW_OFF + (size_t)(      wv*32 + mt*16 + l16)*512 + lk*16);
    awk0[mt] = *(const bf16x8*)(wsc + QKW_OFF + (size_t)(256 + wv*32 + mt*16 + l16)*512 + lk*16);
  }

  // ---- stage A: coalesced copy xt[b][win][px][c] -> sXN (swizzled) ----
  {
    const unsigned short* xw = (const unsigned short*)(wsc + XT_OFF)
                             + ((size_t)Bi*16 + win)*(49*256);
    for (int p = wv; p < 49; p += 8) {
      const u32x2 d = *(const u32x2*)(xw + p*256 + lane*4);
      *(u32x2*)(smem + SXN_AT(p, lane*8)) = d;
    }
  }
  __syncthreads();

  // ---- qk GEMM: aq/ak = D[d][px] C-frags (kt=0 peeled with prefetched weights) ----
  f32x4 aq[2][4], ak[2][4];
  {
    bf16x8 bx[4];
    #pragma unroll
    for (int nt = 0; nt < 4; ++nt) {
      const int row = nt*16 + l16, rc = row < 49 ? row : 48;
      bx[nt] = *(const bf16x8*)(smem + SXN_AT(rc, lk*16));
    }
    #pragma unroll
    for (int mt = 0; mt < 2; ++mt)
      #pragma unroll
      for (int nt = 0; nt < 4; ++nt) {
        aq[mt][nt] = MFMA(awq0[mt], bx[nt], ZERO4);
        ak[mt][nt] = MFMA(awk0[mt], bx[nt], ZERO4);
      }
  }
  #pragma unroll 2
  for (int kt = 1; kt < 8; ++kt) {
    bf16x8 bx[4];
    #pragma unroll
    for (int nt = 0; nt < 4; ++nt) {
      const int row = nt*16 + l16, rc = row < 49 ? row : 48;
      bx[nt] = *(const bf16x8*)(smem + SXN_AT(rc, kt*64 + lk*16));
    }
    #pragma unroll
    for (int mt = 0; mt < 2; ++mt) {
      const bf16x8 awq = *(const bf16x8*)(wsc + QKW_OFF + (size_t)(      wv*32 + mt*16 + l16)*512 + kt*64 + lk*16);
      const bf16x8 awk = *(const bf16x8*)(wsc + QKW_OFF + (size_t)(256 + wv*32 + mt*16 + l16)*512 + kt*64 + lk*16);
      #pragma unroll
      for (int nt = 0; nt < 4; ++nt) {
        aq[mt][nt] = MFMA(awq, bx[nt], aq[mt][nt]);
        ak[mt][nt] = MFMA(awk, bx[nt], ak[mt][nt]);
      }
    }
  }
  { // + qk bias (per d row)
    const f32x4 bq0 = *(const f32x4*)(qk_b +       wv*32 +      lk*4);
    const f32x4 bq1 = *(const f32x4*)(qk_b +       wv*32 + 16 + lk*4);
    const f32x4 bk0 = *(const f32x4*)(qk_b + 256 + wv*32 +      lk*4);
    const f32x4 bk1 = *(const f32x4*)(qk_b + 256 + wv*32 + 16 + lk*4);
    #pragma unroll
    for (int nt = 0; nt < 4; ++nt) {
      aq[0][nt] += bq0; aq[1][nt] += bq1; ak[0][nt] += bk0; ak[1][nt] += bk1;
    }
  }

  // ---- spill q/k to scratch [px][ q: bytes 0..63 | k: bytes 64..127 ], rows 0..48 ----
  #pragma unroll
  for (int nt = 0; nt < 4; ++nt) {
    const int px = nt*16 + l16;
    if (px < 49) {
      #pragma unroll
      for (int mt = 0; mt < 2; ++mt) {
        u32x2 pq  = { cvtpk(aq[mt][nt][0], aq[mt][nt][1]), cvtpk(aq[mt][nt][2], aq[mt][nt][3]) };
        u32x2 pk2 = { cvtpk(ak[mt][nt][0], ak[mt][nt][1]), cvtpk(ak[mt][nt][2], ak[mt][nt][3]) };
        *(u32x2*)(smem + RG_AT(SCR, px,      (mt*16 + lk*4)*2)) = pq;
        *(u32x2*)(smem + RG_AT(SCR, px, 64 + (mt*16 + lk*4)*2)) = pk2;
      }
    }
  }
  CBAR();

  // ---- reload q/k as A/B fragments (round-2 pinned pattern) ----
  bf16x8 qa[4], kb[4];
  #pragma unroll
  for (int t = 0; t < 4; ++t) {
    const int row = t*16 + l16, rc = row < 49 ? row : 48;
    qa[t] = *(const bf16x8*)(smem + RG_AT(SCR, rc,      lk*16));
    kb[t] = *(const bf16x8*)(smem + RG_AT(SCR, rc, 64 + lk*16));
  }

  // ---- QK^T: S[q][k] + bias (round-2 orientation) ----
  f32x4 s[4][4];
  {
    const float scale = 0.17677669529663689f;
    const float* bxp = (const float*)(wsc + BIAS_OFF) + (size_t)(win*8 + wv)*4096 + lane*4;
    #pragma unroll
    for (int mt = 0; mt < 4; ++mt)
      #pragma unroll
      for (int nt = 0; nt < 4; ++nt) {
        f32x4 z = MFMA(qa[mt], kb[nt], ZERO4);
        s[mt][nt] = z*scale + *(const f32x4*)(bxp + (mt*4 + nt)*256);
      }
  }
  // ---- softmax over k (nt regs + l16 lanes) for each q-row (mt, r) ----
  #pragma unroll
  for (int mt = 0; mt < 4; ++mt) {
    #pragma unroll
    for (int r = 0; r < 4; ++r) {
      float mx = fmaxf(fmaxf(s[mt][0][r], s[mt][1][r]), fmaxf(s[mt][2][r], s[mt][3][r]));
      mx = fmaxf(mx, __shfl_xor(mx, 1)); mx = fmaxf(mx, __shfl_xor(mx, 2));
      mx = fmaxf(mx, __shfl_xor(mx, 4)); mx = fmaxf(mx, __shfl_xor(mx, 8));
      const float e0 = __expf(s[mt][0][r]-mx), e1 = __expf(s[mt][1][r]-mx);
      const float e2 = __expf(s[mt][2][r]-mx), e3 = __expf(s[mt][3][r]-mx);
      float sm = e0+e1+e2+e3;
      sm += __shfl_xor(sm, 1); sm += __shfl_xor(sm, 2);
      sm += __shfl_xor(sm, 4); sm += __shfl_xor(sm, 8);
      const float inv = 1.f/sm;
      s[mt][0][r] = e0*inv; s[mt][1][r] = e1*inv;
      s[mt][2][r] = e2*inv; s[mt][3][r] = e3*inv;
    }
  }
  // ---- store P [q][k] rows 0..48 (all 64 k cols; masked cols are exactly 0) ----
  #pragma unroll
  for (int mt = 0; mt < 4; ++mt)
    #pragma unroll
    for (int r = 0; r < 4; ++r) {
      const int q = mt*16 + lk*4 + r;
      if (q < 49) {
        #pragma unroll
        for (int nt = 0; nt < 4; ++nt)
          *(unsigned short*)(smem + RG_AT(SCR, q, (nt*16 + l16)*2)) = f2bu(s[mt][nt][r]);
      }
    }
  CBAR();

  // ---- va GEMM: av = D[px][ch] C-frags ----
  f32x4 av[4][4];
  #pragma unroll
  for (int mt = 0; mt < 4; ++mt)
    #pragma unroll
    for (int nt = 0; nt < 4; ++nt) av[mt][nt] = ZERO4;
  #pragma unroll 2
  for (int kt = 0; kt < 8; ++kt) {
    bf16x8 ax[4], bw[4];
    #pragma unroll
    for (int t = 0; t < 4; ++t) {
      const int row = t*16 + l16, rc = row < 49 ? row : 48;
      ax[t] = *(const bf16x8*)(smem + SXN_AT(rc, kt*64 + lk*16));
      bw[t] = *(const bf16x8*)(wsc + VW_OFF + (size_t)(wv*64 + t*16 + l16)*512 + kt*64 + lk*16);
    }
    #pragma unroll
    for (int mt = 0; mt < 4; ++mt)
      #pragma unroll
      for (int nt = 0; nt < 4; ++nt) av[mt][nt] = MFMA(ax[mt], bw[nt], av[mt][nt]);
  }
  { // + v bias (per ch col)
    #pragma unroll
    for (int nt = 0; nt < 4; ++nt) {
      const float vb = v_b[wv*64 + nt*16 + l16];
      #pragma unroll
      for (int mt = 0; mt < 4; ++mt)
        #pragma unroll
        for (int r = 0; r < 4; ++r) av[mt][nt][r] += vb;
    }
  }

  // ---- read P as B-frags (round-2 pinned pattern) ----
  bf16x8 fpb[4][2];
  #pragma unroll
  for (int t = 0; t < 4; ++t) {
    const int row = t*16 + l16, rc = row < 49 ? row : 48;
    #pragma unroll
    for (int kt = 0; kt < 2; ++kt)
      fpb[t][kt] = *(const bf16x8*)(smem + RG_AT(SCR, rc, (kt*32 + lk*8)*2));
  }
  CBAR();

  // ---- PV in two 32-ch halves through scratch [ch][px] (rows 0..31) ----
  f32x4 o[4][4];
  #pragma unroll
  for (int h2 = 0; h2 < 2; ++h2) {
    #pragma unroll
    for (int tc = 0; tc < 2; ++tc) {
      const int nt = h2*2 + tc;          // global ch tile
      const int chrow = tc*16 + l16;     // row within this half
      #pragma unroll
      for (int mt = 0; mt < 4; ++mt) {
        u32x2 pv = { cvtpk(av[mt][nt][0], av[mt][nt][1]), cvtpk(av[mt][nt][2], av[mt][nt][3]) };
        *(u32x2*)(smem + RG_AT(SCR, chrow, (mt*16 + lk*4)*2)) = pv;
      }
    }
    CBAR();
    #pragma unroll
    for (int tc = 0; tc < 2; ++tc) {
      const int mtc = h2*2 + tc;
      const bf16x8 a0 = *(const bf16x8*)(smem + RG_AT(SCR, tc*16 + l16, (     lk*8)*2));
      const bf16x8 a1 = *(const bf16x8*)(smem + RG_AT(SCR, tc*16 + l16, (32 + lk*8)*2));
      #pragma unroll
      for (int nt = 0; nt < 4; ++nt) {
        f32x4 z = MFMA(a0, fpb[nt][0], ZERO4);
        o[mtc][nt] = MFMA(a1, fpb[nt][1], z);
      }
    }
    CBAR();
  }

  // ---- store attention out [q][ch] into region wv ----
  #pragma unroll
  for (int mtc = 0; mtc < 4; ++mtc)
    #pragma unroll
    for (int nt = 0; nt < 4; ++nt) {
      const int q = nt*16 + l16;
      if (q < 49) {
        u32x2 pk = { cvtpk(o[mtc][nt][0], o[mtc][nt][1]), cvtpk(o[mtc][nt][2], o[mtc][nt][3]) };
        *(u32x2*)(smem + RG_AT(RGB(wv), q, (mtc*16 + lk*4)*2)) = pk;
      }
    }
  __syncthreads();

  // ---- post-LN (512 ch) + gelu, in place on regions ----
  {
    const int px = tid >> 3, j = tid & 7;
    if (px < 49) {
      bf16x8 f[8];
      float s1 = 0.f, s2 = 0.f;
      #pragma unroll
      for (int c8 = 0; c8 < 8; ++c8) {
        f[c8] = *(const bf16x8*)(smem + RG_AT(RGB(j), px, c8*16));
        #pragma unroll
        for (int i = 0; i < 8; ++i) { const float v = (float)f[c8][i]; s1 += v; s2 += v*v; }
      }
      s1 += __shfl_xor(s1, 1); s1 += __shfl_xor(s1, 2); s1 += __shfl_xor(s1, 4);
      s2 += __shfl_xor(s2, 1); s2 += __shfl_xor(s2, 2); s2 += __shfl_xor(s2, 4);
      const float mu = s1*(1.f/512.f);
      const float rs = rsqrtf(s2*(1.f/512.f) - mu*mu + 1e-5f);
      #pragma unroll
      for (int c8 = 0; c8 < 8; ++c8) {
        const f32x4 pw0 = *(const f32x4*)(post_w + j*64 + c8*8);
        const f32x4 pw1 = *(const f32x4*)(post_w + j*64 + c8*8 + 4);
        const f32x4 pb0 = *(const f32x4*)(post_b + j*64 + c8*8);
        const f32x4 pb1 = *(const f32x4*)(post_b + j*64 + c8*8 + 4);
        float g[8];
        #pragma unroll
        for (int i = 0; i < 8; ++i) {
          const float v = (float)f[c8][i];
          const float w = i < 4 ? pw0[i] : pw1[i-4];
          const float b = i < 4 ? pb0[i] : pb1[i-4];
          g[i] = gelu_f((v-mu)*rs*w + b);
        }
        u32x4v pk = { cvtpk(g[0],g[1]), cvtpk(g[2],g[3]), cvtpk(g[4],g[5]), cvtpk(g[6],g[7]) };
        *(u32x4v*)(smem + RG_AT(RGB(j), px, c8*16)) = pk;
      }
    }
  }
  __syncthreads();

  // ---- proj GEMM (attn half): D[o][px], K=512 from regions ----
  f32x4 pacc[2][4];
  #pragma unroll
  for (int mt = 0; mt < 2; ++mt)
    #pragma unroll
    for (int nt = 0; nt < 4; ++nt) pacc[mt][nt] = ZERO4;
  for (int j8 = 0; j8 < 8; ++j8) {
    #pragma unroll
    for (int kt2 = 0; kt2 < 2; ++kt2) {
      bf16x8 b[4];
      #pragma unroll
      for (int nt = 0; nt < 4; ++nt) {
        const int row = nt*16 + l16, rc = row < 49 ? row : 48;
        b[nt] = *(const bf16x8*)(smem + RG_AT(RGB(j8), rc, (kt2*32 + lk*8)*2));
      }
      const int kg = j8*64 + kt2*32 + lk*8;
      #pragma unroll
      for (int mt = 0; mt < 2; ++mt) {
        const bf16x8 aw = *(const bf16x8*)(wsc + PJW_OFF + (size_t)(wv*32 + mt*16 + l16)*2048 + kg*2);
        #pragma unroll
        for (int nt = 0; nt < 4; ++nt) pacc[mt][nt] = MFMA(aw, b[nt], pacc[mt][nt]);
      }
    }
  }

  // ---- idle-v: wave wv computes idle ch [512+wv*64, +64) over all px -> its region ----
  __syncthreads();   // all waves done READING regions (attn proj) before overwrite
  {
    f32x4 ia[4][4];
    #pragma unroll
    for (int mt = 0; mt < 4; ++mt)
      #pragma unroll
      for (int nt = 0; nt < 4; ++nt) ia[mt][nt] = ZERO4;
    #pragma unroll 2
    for (int kt = 0; kt < 8; ++kt) {
      bf16x8 b[4], aw[4];
      #pragma unroll
      for (int t = 0; t < 4; ++t) {
        const int row = t*16 + l16, rc = row < 49 ? row : 48;
        b[t]  = *(const bf16x8*)(smem + SXN_AT(rc, kt*64 + lk*16));
        aw[t] = *(const bf16x8*)(wsc + VW_OFF + (size_t)(512 + wv*64 + t*16 + l16)*512 + kt*64 + lk*16);
      }
      #pragma unroll
      for (int mt = 0; mt < 4; ++mt)
        #pragma unroll
        for (int nt = 0; nt < 4; ++nt) ia[mt][nt] = MFMA(aw[mt], b[nt], ia[mt][nt]);
    }
    // + v_b, gelu, pack to region [px][64 ch]  (D[ch][px]: row=ch(mt,lk,r), col=px(nt,l16))
    #pragma unroll
    for (int mt = 0; mt < 4; ++mt) {
      const f32x4 vb = *(const f32x4*)(v_b + 512 + wv*64 + mt*16 + lk*4);
      #pragma unroll
      for (int nt = 0; nt < 4; ++nt) {
        const int px = nt*16 + l16;
        if (px < 49) {
          u32x2 pk = { cvtpk(gelu_f(ia[mt][nt][0]+vb[0]), gelu_f(ia[mt][nt][1]+vb[1])),
                       cvtpk(gelu_f(ia[mt][nt][2]+vb[2]), gelu_f(ia[mt][nt][3]+vb[3])) };
          *(u32x2*)(smem + RG_AT(RGB(wv), px, (mt*16 + lk*4)*2)) = pk;
        }
      }
    }
  }
  __syncthreads();

  // ---- proj GEMM (idle half): K=512 from regions, kg offset 512 ----
  for (int j8 = 0; j8 < 8; ++j8) {
    #pragma unroll
    for (int kt2 = 0; kt2 < 2; ++kt2) {
      bf16x8 b[4];
      #pragma unroll
      for (int nt = 0; nt < 4; ++nt) {
        const int row = nt*16 + l16, rc = row < 49 ? row : 48;
        b[nt] = *(const bf16x8*)(smem + RG_AT(RGB(j8), rc, (kt2*32 + lk*8)*2));
      }
      const int kg = 512 + j8*64 + kt2*32 + lk*8;
      #pragma unroll
      for (int mt = 0; mt < 2; ++mt) {
        const bf16x8 aw = *(const bf16x8*)(wsc + PJW_OFF + (size_t)(wv*32 + mt*16 + l16)*2048 + kg*2);
        #pragma unroll
        for (int nt = 0; nt < 4; ++nt) pacc[mt][nt] = MFMA(aw, b[nt], pacc[mt][nt]);
      }
    }
  }

  // ---- epilogue: + proj_b + residual, roll(+2,+2) store (R0 fused form) ----
  {
    int xoff[4], roff[4];
    #pragma unroll
    for (int nt = 0; nt < 4; ++nt) {
      const int px = nt*16 + l16;
      const int pc = px < 49 ? px : 48;
      const int gh = (pc/7)*4 + n1, gw = (pc%7)*4 + n2;
      xoff[nt] = gh*28 + gw;
      int rh = gh + 2; if (rh >= 28) rh -= 28;
      int rw = gw + 2; if (rw >= 28) rw -= 28;
      roff[nt] = rh*28 + rw;
    }
    #pragma unroll
    for (int mt = 0; mt < 2; ++mt) {
      #pragma unroll
      for (int r = 0; r < 4; ++r) {
        const int o2 = wv*32 + mt*16 + lk*4 + r;
        const float pb = proj_b[o2];
        const size_t cb = xbase + (size_t)o2*784;
        #pragma unroll
        for (int nt = 0; nt < 4; ++nt) {
          if (nt*16 + l16 < 49)
            out[cb + roff[nt]] = x[cb + xoff[nt]] + pacc[mt][nt][r] + pb;
        }
      }
    }
  }
}

extern "C" void kernel_launch(void* const* d_in, const int* in_sizes, int n_in,
                              void* d_out, int out_size, void* d_ws, size_t ws_size,
                              hipStream_t stream) {
  const float* x      = (const float*)d_in[0];
  const float* pre_w  = (const float*)d_in[1];
  const float* pre_b  = (const float*)d_in[2];
  const float* qk_w   = (const float*)d_in[3];
  const float* qk_b   = (const float*)d_in[4];
  const float* v_w    = (const float*)d_in[5];
  const float* v_b    = (const float*)d_in[6];
  const float* post_w = (const float*)d_in[7];
  const float* post_b = (const float*)d_in[8];
  const float* proj_w = (const float*)d_in[9];
  const float* proj_b = (const float*)d_in[10];
  const float* rpb    = (const float*)d_in[11];
  float* outp = (float*)d_out;
  char* wsc = (char*)d_ws;

  hipFuncSetAttribute((const void*)emo_main, hipFuncAttributeMaxDynamicSharedMemorySize, 81920);

  emo_prep<<<4288, 256, 0, stream>>>(x, pre_w, pre_b, qk_w, v_w, proj_w, rpb,
                                     (unsigned short*)(wsc + XT_OFF),
                                     (unsigned short*)wsc, (float*)(wsc + BIAS_OFF));
  emo_main<<<1024, 512, 76288, stream>>>(x, qk_b, v_b, post_w, post_b, proj_b,
                                         (const char*)wsc, outp);
}

// Round 9
// 303.782 us; speedup vs baseline: 1.1614x; 1.1614x over previous
//
#include <hip/hip_runtime.h>
#include <hip/hip_bf16.h>

typedef __bf16          bf16x8 __attribute__((ext_vector_type(8)));
typedef float           f32x4  __attribute__((ext_vector_type(4)));
typedef unsigned int    u32x2  __attribute__((ext_vector_type(2)));
typedef unsigned int    u32x4v __attribute__((ext_vector_type(4)));

// d_ws layout (bytes)
#define QKW_OFF  0           // 512*256 bf16                        (262144)
#define VW_OFF   262144      // 1024*256 bf16                       (524288)
#define PJW_OFF  786432      // 256*1024 bf16                       (524288)
#define BIAS_OFF 1310720     // [16 win][8 h][16 chunk][64 lane][4 r] f32 (2097152)
#define XT_OFF   70516736    // [64 b][16 win][49 px][256 c] bf16   (25690112)

#define MFMA(a,b,c) __builtin_amdgcn_mfma_f32_16x16x32_bf16((a),(b),(c),0,0,0)
#define ZERO4 ((f32x4){0.f,0.f,0.f,0.f})
#define CBAR() asm volatile("" ::: "memory")

// LDS map (76288 B):
//   [0, 25088)        sXN [49 px][256 c] bf16, row 512 B, swz ^((row&7)<<4)
//   [25088, 76288)    8 regions of 6400 B (50*128, 128-aligned bases):
//                     per-wave scratch during attention (q/k -> P -> va),
//                     then out[49 q][64 ch] row 128 B; then idle-v [49 px][64 ch].
#define SXN_AT(row, byte)      ((((row)*512 + (byte))) ^ ((((row)&7))<<4))
#define RGB(j)                 (25088 + (j)*6400)
#define RG_AT(base, row, byte) (((base) + (row)*128 + (byte)) ^ (((row)&7)<<4))

static __device__ __forceinline__ unsigned cvtpk(float lo, float hi){
  unsigned r;
  asm("v_cvt_pk_bf16_f32 %0, %1, %2" : "=v"(r) : "v"(lo), "v"(hi));
  return r;
}
static __device__ __forceinline__ unsigned short f2bu(float f) {
  unsigned u = __builtin_bit_cast(unsigned, f);
  return (unsigned short)((u + 0x7FFFu + ((u >> 16) & 1u)) >> 16);
}
static __device__ __forceinline__ float gelu_f(float v){
  // v * sigmoid(1.5957691*v*(1+0.044715 v^2)) == tanh-form gelu, |err| < ~1e-3
  return v / (1.f + __expf(-1.5957691216057308f*v*(1.f + 0.044715f*v*v)));
}

// ---------------- prep: weights->bf16 AND bias table, merged (one launch) ----------------
// blocks [0,2560): weight convert; blocks [2560,2688): bias table.
__global__ void emo_prep_wb(const float* __restrict__ qk_w, const float* __restrict__ v_w,
                            const float* __restrict__ proj_w, const float* __restrict__ rpb,
                            unsigned short* __restrict__ w16, float* __restrict__ bx) {
  const int blk = blockIdx.x;
  if (blk < 2560) {
    int i = blk * 256 + threadIdx.x;
    if (i >= 655360) return;
    float v;
    if (i < 131072)      v = qk_w[i];
    else if (i < 393216) v = v_w[i - 131072];
    else                 v = proj_w[i - 393216];
    unsigned u = __builtin_bit_cast(unsigned, v);
    w16[i] = (unsigned short)((u + 0x7FFFu + ((u >> 16) & 1u)) >> 16);
  } else {
    const int wh = blk - 2560;          // win*8 + h
    const int win = wh >> 3, h = wh & 7;
    for (int e = threadIdx.x; e < 4096; e += 256) {
      const int chunk = e >> 8, lane = (e >> 2) & 63, r = e & 3;
      const int mt = chunk >> 2, nt = chunk & 3;
      const int m = mt*16 + (lane >> 4)*4 + r;   // query pixel
      const int n = nt*16 + (lane & 15);         // key pixel
      float v;
      if (n >= 49)      v = -1e30f;              // softmax mask over key dim
      else if (m >= 49) v = 0.f;
      else {
        const int dI = m/7 - n/7 + 6;
        const int dJ = m%7 - n%7 + 6;
        v = rpb[(win*169 + dI*13 + dJ)*8 + h];
      }
      bx[wh*4096 + e] = v;
    }
  }
}

// ---------------- prep: pre-LN + window transform, NCHW f32 -> [b][win][px][c] bf16 ----------------
// block = (chunk of 32 px, b). Static 35 KB LDS -> 4 blocks/CU.
__global__ __launch_bounds__(256)
void emo_prep_x(const float* __restrict__ x, const float* __restrict__ pre_w,
                const float* __restrict__ pre_b, unsigned short* __restrict__ xt) {
  __shared__ float lv[32*257];     // 32896 B
  __shared__ float ps1[8][32];
  __shared__ float ps2[8][32];
  const int tid = threadIdx.x, lane = tid & 63, wv = tid >> 6;
  const int l32 = lane & 31, hp = lane >> 5;
  const int chunk = blockIdx.x, b = blockIdx.y;
  const int s = chunk*32 + l32;            // spatial index h*28+w
  const bool ok = s < 784;
  const float* xb = x + (size_t)b*200704;  // 256*784
  float s1 = 0.f, s2 = 0.f;
  const int c0 = wv*64 + hp*32;
  for (int ci = 0; ci < 32; ++ci) {
    const int c = c0 + ci;
    const float v = ok ? xb[c*784 + s] : 0.f;
    lv[l32*257 + c] = v;
    s1 += v; s2 += v*v;
  }
  ps1[wv*2 + hp][l32] = s1;
  ps2[wv*2 + hp][l32] = s2;
  __syncthreads();
  const int px = tid & 31, j = tid >> 5;
  const int sp = chunk*32 + px;
  if (sp < 784) {
    float t1 = 0.f, t2 = 0.f;
    #pragma unroll
    for (int k = 0; k < 8; ++k) { t1 += ps1[k][px]; t2 += ps2[k][px]; }
    const float mu = t1*(1.f/256.f);
    const float rs = rsqrtf(t2*(1.f/256.f) - mu*mu + 1e-5f);
    const int h = sp/28, w = sp - h*28;
    const int win = (h & 3)*4 + (w & 3);         // n1*4 + n2
    const int wpx = (h >> 2)*7 + (w >> 2);       // ph*7 + pw
    unsigned short* row = xt + (((size_t)b*16 + win)*49 + wpx)*256 + j*32;
    #pragma unroll
    for (int g = 0; g < 4; ++g) {
      float gg[8];
      #pragma unroll
      for (int i2 = 0; i2 < 8; ++i2) {
        const int c = j*32 + g*8 + i2;
        gg[i2] = (lv[px*257 + c] - mu)*rs*pre_w[c] + pre_b[c];
      }
      u32x4v pk = { cvtpk(gg[0],gg[1]), cvtpk(gg[2],gg[3]), cvtpk(gg[4],gg[5]), cvtpk(gg[6],gg[7]) };
      *(u32x4v*)(row + g*8) = pk;
    }
  }
}

// ---------------- main fused kernel (R7 structure; idle-v direct to regions) ----------------
// Input path: coalesced xt read. Output: fused residual+roll store (needs R0's
// batch-grouped mapping for L2 write-merging of interleaved window lines — R6 lesson).
// Idle-v: SAME two 32-ch halves / ia[2][4] register profile as R7 (R8's ia[4][4]
// merge spilled: WRITE 184->400 MB), but each half writes directly into the wave's
// own region (same scatter pattern as the attention-out store) instead of the SC
// overlay: removes 2 of 4 idle-phase barriers + 64 KB/block LDS round-trip.
__global__ __launch_bounds__(512, 4)
void emo_main(const float* __restrict__ x,
              const float* __restrict__ qk_b,  const float* __restrict__ v_b,
              const float* __restrict__ post_w,const float* __restrict__ post_b,
              const float* __restrict__ proj_b,
              const char*  __restrict__ wsc,
              float* __restrict__ out)
{
  extern __shared__ char smem[];
  const int tid  = threadIdx.x;
  const int lane = tid & 63;
  const int l16  = lane & 15;
  const int lk   = lane >> 4;
  const int wv   = tid >> 6;                 // wave = head
  const int bid  = blockIdx.x;
  const int Bi   = (bid & 7) * 8 + (bid >> 7);   // XCD swizzle (bijective, R0 form)
  const int win  = (bid >> 3) & 15;
  const int n1   = win >> 2, n2 = win & 3;
  const size_t xbase = (size_t)Bi * (256*784);
  const int SCR  = RGB(wv);                  // per-wave scratch base

  // ---- stage A: coalesced copy xt[b][win][px][c] -> sXN (swizzled) ----
  {
    const unsigned short* xw = (const unsigned short*)(wsc + XT_OFF)
                             + ((size_t)Bi*16 + win)*(49*256);
    for (int p = wv; p < 49; p += 8) {
      const u32x2 d = *(const u32x2*)(xw + p*256 + lane*4);
      *(u32x2*)(smem + SXN_AT(p, lane*8)) = d;
    }
  }
  __syncthreads();

  // ---- qk GEMM: aq/ak = D[d][px] C-frags ----
  f32x4 aq[2][4], ak[2][4];
  #pragma unroll
  for (int mt = 0; mt < 2; ++mt)
    #pragma unroll
    for (int nt = 0; nt < 4; ++nt) { aq[mt][nt] = ZERO4; ak[mt][nt] = ZERO4; }
  #pragma unroll 2
  for (int kt = 0; kt < 8; ++kt) {
    bf16x8 bx[4];
    #pragma unroll
    for (int nt = 0; nt < 4; ++nt) {
      const int row = nt*16 + l16, rc = row < 49 ? row : 48;
      bx[nt] = *(const bf16x8*)(smem + SXN_AT(rc, kt*64 + lk*16));
    }
    #pragma unroll
    for (int mt = 0; mt < 2; ++mt) {
      const bf16x8 awq = *(const bf16x8*)(wsc + QKW_OFF + (size_t)(      wv*32 + mt*16 + l16)*512 + kt*64 + lk*16);
      const bf16x8 awk = *(const bf16x8*)(wsc + QKW_OFF + (size_t)(256 + wv*32 + mt*16 + l16)*512 + kt*64 + lk*16);
      #pragma unroll
      for (int nt = 0; nt < 4; ++nt) {
        aq[mt][nt] = MFMA(awq, bx[nt], aq[mt][nt]);
        ak[mt][nt] = MFMA(awk, bx[nt], ak[mt][nt]);
      }
    }
  }
  { // + qk bias (per d row)
    const f32x4 bq0 = *(const f32x4*)(qk_b +       wv*32 +      lk*4);
    const f32x4 bq1 = *(const f32x4*)(qk_b +       wv*32 + 16 + lk*4);
    const f32x4 bk0 = *(const f32x4*)(qk_b + 256 + wv*32 +      lk*4);
    const f32x4 bk1 = *(const f32x4*)(qk_b + 256 + wv*32 + 16 + lk*4);
    #pragma unroll
    for (int nt = 0; nt < 4; ++nt) {
      aq[0][nt] += bq0; aq[1][nt] += bq1; ak[0][nt] += bk0; ak[1][nt] += bk1;
    }
  }

  // ---- spill q/k to scratch [px][ q: bytes 0..63 | k: bytes 64..127 ], rows 0..48 ----
  #pragma unroll
  for (int nt = 0; nt < 4; ++nt) {
    const int px = nt*16 + l16;
    if (px < 49) {
      #pragma unroll
      for (int mt = 0; mt < 2; ++mt) {
        u32x2 pq  = { cvtpk(aq[mt][nt][0], aq[mt][nt][1]), cvtpk(aq[mt][nt][2], aq[mt][nt][3]) };
        u32x2 pk2 = { cvtpk(ak[mt][nt][0], ak[mt][nt][1]), cvtpk(ak[mt][nt][2], ak[mt][nt][3]) };
        *(u32x2*)(smem + RG_AT(SCR, px,      (mt*16 + lk*4)*2)) = pq;
        *(u32x2*)(smem + RG_AT(SCR, px, 64 + (mt*16 + lk*4)*2)) = pk2;
      }
    }
  }
  CBAR();

  // ---- reload q/k as A/B fragments (round-2 pinned pattern) ----
  bf16x8 qa[4], kb[4];
  #pragma unroll
  for (int t = 0; t < 4; ++t) {
    const int row = t*16 + l16, rc = row < 49 ? row : 48;
    qa[t] = *(const bf16x8*)(smem + RG_AT(SCR, rc,      lk*16));
    kb[t] = *(const bf16x8*)(smem + RG_AT(SCR, rc, 64 + lk*16));
  }

  // ---- QK^T: S[q][k] + bias (round-2 orientation) ----
  f32x4 s[4][4];
  {
    const float scale = 0.17677669529663689f;
    const float* bxp = (const float*)(wsc + BIAS_OFF) + (size_t)(win*8 + wv)*4096 + lane*4;
    #pragma unroll
    for (int mt = 0; mt < 4; ++mt)
      #pragma unroll
      for (int nt = 0; nt < 4; ++nt) {
        f32x4 z = MFMA(qa[mt], kb[nt], ZERO4);
        s[mt][nt] = z*scale + *(const f32x4*)(bxp + (mt*4 + nt)*256);
      }
  }
  // ---- softmax over k (nt regs + l16 lanes) for each q-row (mt, r) ----
  #pragma unroll
  for (int mt = 0; mt < 4; ++mt) {
    #pragma unroll
    for (int r = 0; r < 4; ++r) {
      float mx = fmaxf(fmaxf(s[mt][0][r], s[mt][1][r]), fmaxf(s[mt][2][r], s[mt][3][r]));
      mx = fmaxf(mx, __shfl_xor(mx, 1)); mx = fmaxf(mx, __shfl_xor(mx, 2));
      mx = fmaxf(mx, __shfl_xor(mx, 4)); mx = fmaxf(mx, __shfl_xor(mx, 8));
      const float e0 = __expf(s[mt][0][r]-mx), e1 = __expf(s[mt][1][r]-mx);
      const float e2 = __expf(s[mt][2][r]-mx), e3 = __expf(s[mt][3][r]-mx);
      float sm = e0+e1+e2+e3;
      sm += __shfl_xor(sm, 1); sm += __shfl_xor(sm, 2);
      sm += __shfl_xor(sm, 4); sm += __shfl_xor(sm, 8);
      const float inv = 1.f/sm;
      s[mt][0][r] = e0*inv; s[mt][1][r] = e1*inv;
      s[mt][2][r] = e2*inv; s[mt][3][r] = e3*inv;
    }
  }
  // ---- store P [q][k] rows 0..48 (all 64 k cols; masked cols are exactly 0) ----
  #pragma unroll
  for (int mt = 0; mt < 4; ++mt)
    #pragma unroll
    for (int r = 0; r < 4; ++r) {
      const int q = mt*16 + lk*4 + r;
      if (q < 49) {
        #pragma unroll
        for (int nt = 0; nt < 4; ++nt)
          *(unsigned short*)(smem + RG_AT(SCR, q, (nt*16 + l16)*2)) = f2bu(s[mt][nt][r]);
      }
    }
  CBAR();

  // ---- va GEMM: av = D[px][ch] C-frags ----
  f32x4 av[4][4];
  #pragma unroll
  for (int mt = 0; mt < 4; ++mt)
    #pragma unroll
    for (int nt = 0; nt < 4; ++nt) av[mt][nt] = ZERO4;
  #pragma unroll 2
  for (int kt = 0; kt < 8; ++kt) {
    bf16x8 ax[4], bw[4];
    #pragma unroll
    for (int t = 0; t < 4; ++t) {
      const int row = t*16 + l16, rc = row < 49 ? row : 48;
      ax[t] = *(const bf16x8*)(smem + SXN_AT(rc, kt*64 + lk*16));
      bw[t] = *(const bf16x8*)(wsc + VW_OFF + (size_t)(wv*64 + t*16 + l16)*512 + kt*64 + lk*16);
    }
    #pragma unroll
    for (int mt = 0; mt < 4; ++mt)
      #pragma unroll
      for (int nt = 0; nt < 4; ++nt) av[mt][nt] = MFMA(ax[mt], bw[nt], av[mt][nt]);
  }
  { // + v bias (per ch col)
    #pragma unroll
    for (int nt = 0; nt < 4; ++nt) {
      const float vb = v_b[wv*64 + nt*16 + l16];
      #pragma unroll
      for (int mt = 0; mt < 4; ++mt)
        #pragma unroll
        for (int r = 0; r < 4; ++r) av[mt][nt][r] += vb;
    }
  }

  // ---- read P as B-frags (round-2 pinned pattern) ----
  bf16x8 fpb[4][2];
  #pragma unroll
  for (int t = 0; t < 4; ++t) {
    const int row = t*16 + l16, rc = row < 49 ? row : 48;
    #pragma unroll
    for (int kt = 0; kt < 2; ++kt)
      fpb[t][kt] = *(const bf16x8*)(smem + RG_AT(SCR, rc, (kt*32 + lk*8)*2));
  }
  CBAR();

  // ---- PV in two 32-ch halves through scratch [ch][px] (rows 0..31) ----
  f32x4 o[4][4];
  #pragma unroll
  for (int h2 = 0; h2 < 2; ++h2) {
    #pragma unroll
    for (int tc = 0; tc < 2; ++tc) {
      const int nt = h2*2 + tc;          // global ch tile
      const int chrow = tc*16 + l16;     // row within this half
      #pragma unroll
      for (int mt = 0; mt < 4; ++mt) {
        u32x2 pv = { cvtpk(av[mt][nt][0], av[mt][nt][1]), cvtpk(av[mt][nt][2], av[mt][nt][3]) };
        *(u32x2*)(smem + RG_AT(SCR, chrow, (mt*16 + lk*4)*2)) = pv;
      }
    }
    CBAR();
    #pragma unroll
    for (int tc = 0; tc < 2; ++tc) {
      const int mtc = h2*2 + tc;
      const bf16x8 a0 = *(const bf16x8*)(smem + RG_AT(SCR, tc*16 + l16, (     lk*8)*2));
      const bf16x8 a1 = *(const bf16x8*)(smem + RG_AT(SCR, tc*16 + l16, (32 + lk*8)*2));
      #pragma unroll
      for (int nt = 0; nt < 4; ++nt) {
        f32x4 z = MFMA(a0, fpb[nt][0], ZERO4);
        o[mtc][nt] = MFMA(a1, fpb[nt][1], z);
      }
    }
    CBAR();
  }

  // ---- store attention out [q][ch] into region wv ----
  #pragma unroll
  for (int mtc = 0; mtc < 4; ++mtc)
    #pragma unroll
    for (int nt = 0; nt < 4; ++nt) {
      const int q = nt*16 + l16;
      if (q < 49) {
        u32x2 pk = { cvtpk(o[mtc][nt][0], o[mtc][nt][1]), cvtpk(o[mtc][nt][2], o[mtc][nt][3]) };
        *(u32x2*)(smem + RG_AT(RGB(wv), q, (mtc*16 + lk*4)*2)) = pk;
      }
    }
  __syncthreads();

  // ---- post-LN (512 ch) + gelu, in place on regions ----
  {
    const int px = tid >> 3, j = tid & 7;
    if (px < 49) {
      bf16x8 f[8];
      float s1 = 0.f, s2 = 0.f;
      #pragma unroll
      for (int c8 = 0; c8 < 8; ++c8) {
        f[c8] = *(const bf16x8*)(smem + RG_AT(RGB(j), px, c8*16));
        #pragma unroll
        for (int i = 0; i < 8; ++i) { const float v = (float)f[c8][i]; s1 += v; s2 += v*v; }
      }
      s1 += __shfl_xor(s1, 1); s1 += __shfl_xor(s1, 2); s1 += __shfl_xor(s1, 4);
      s2 += __shfl_xor(s2, 1); s2 += __shfl_xor(s2, 2); s2 += __shfl_xor(s2, 4);
      const float mu = s1*(1.f/512.f);
      const float rs = rsqrtf(s2*(1.f/512.f) - mu*mu + 1e-5f);
      #pragma unroll
      for (int c8 = 0; c8 < 8; ++c8) {
        const f32x4 pw0 = *(const f32x4*)(post_w + j*64 + c8*8);
        const f32x4 pw1 = *(const f32x4*)(post_w + j*64 + c8*8 + 4);
        const f32x4 pb0 = *(const f32x4*)(post_b + j*64 + c8*8);
        const f32x4 pb1 = *(const f32x4*)(post_b + j*64 + c8*8 + 4);
        float g[8];
        #pragma unroll
        for (int i = 0; i < 8; ++i) {
          const float v = (float)f[c8][i];
          const float w = i < 4 ? pw0[i] : pw1[i-4];
          const float b = i < 4 ? pb0[i] : pb1[i-4];
          g[i] = gelu_f((v-mu)*rs*w + b);
        }
        u32x4v pk = { cvtpk(g[0],g[1]), cvtpk(g[2],g[3]), cvtpk(g[4],g[5]), cvtpk(g[6],g[7]) };
        *(u32x4v*)(smem + RG_AT(RGB(j), px, c8*16)) = pk;
      }
    }
  }
  __syncthreads();

  // ---- proj GEMM (attn half): D[o][px], K=512 from regions ----
  f32x4 pacc[2][4];
  #pragma unroll
  for (int mt = 0; mt < 2; ++mt)
    #pragma unroll
    for (int nt = 0; nt < 4; ++nt) pacc[mt][nt] = ZERO4;
  for (int j8 = 0; j8 < 8; ++j8) {
    #pragma unroll
    for (int kt2 = 0; kt2 < 2; ++kt2) {
      bf16x8 b[4];
      #pragma unroll
      for (int nt = 0; nt < 4; ++nt) {
        const int row = nt*16 + l16, rc = row < 49 ? row : 48;
        b[nt] = *(const bf16x8*)(smem + RG_AT(RGB(j8), rc, (kt2*32 + lk*8)*2));
      }
      const int kg = j8*64 + kt2*32 + lk*8;
      #pragma unroll
      for (int mt = 0; mt < 2; ++mt) {
        const bf16x8 aw = *(const bf16x8*)(wsc + PJW_OFF + (size_t)(wv*32 + mt*16 + l16)*2048 + kg*2);
        #pragma unroll
        for (int nt = 0; nt < 4; ++nt) pacc[mt][nt] = MFMA(aw, b[nt], pacc[mt][nt]);
      }
    }
  }

  // ---- idle-v: two 32-ch halves (ia[2][4], R7 register profile), direct to region wv ----
  __syncthreads();   // all waves done READING regions (attn proj) before overwrite
  #pragma unroll 1
  for (int chh = 0; chh < 2; ++chh) {
    f32x4 ia[2][4];
    #pragma unroll
    for (int mt = 0; mt < 2; ++mt)
      #pragma unroll
      for (int nt = 0; nt < 4; ++nt) ia[mt][nt] = ZERO4;
    const int c0 = 512 + wv*64 + chh*32;   // this half's idle ch base
    #pragma unroll 2
    for (int kt = 0; kt < 8; ++kt) {
      bf16x8 b[4];
      #pragma unroll
      for (int nt = 0; nt < 4; ++nt) {
        const int row = nt*16 + l16, rc = row < 49 ? row : 48;
        b[nt] = *(const bf16x8*)(smem + SXN_AT(rc, kt*64 + lk*16));
      }
      #pragma unroll
      for (int mt = 0; mt < 2; ++mt) {
        const bf16x8 aw = *(const bf16x8*)(wsc + VW_OFF + (size_t)(c0 + mt*16 + l16)*512 + kt*64 + lk*16);
        #pragma unroll
        for (int nt = 0; nt < 4; ++nt) ia[mt][nt] = MFMA(aw, b[nt], ia[mt][nt]);
      }
    }
    // + v_b, gelu, pack into region wv [px][64 ch] (same scatter as attn-out store)
    #pragma unroll
    for (int mt = 0; mt < 2; ++mt) {
      const f32x4 vb = *(const f32x4*)(v_b + c0 + mt*16 + lk*4);
      #pragma unroll
      for (int nt = 0; nt < 4; ++nt) {
        const int px = nt*16 + l16;
        if (px < 49) {
          const int chl = chh*32 + mt*16 + lk*4;   // col within region (0..63)
          u32x2 pk = { cvtpk(gelu_f(ia[mt][nt][0]+vb[0]), gelu_f(ia[mt][nt][1]+vb[1])),
                       cvtpk(gelu_f(ia[mt][nt][2]+vb[2]), gelu_f(ia[mt][nt][3]+vb[3])) };
          *(u32x2*)(smem + RG_AT(RGB(wv), px, chl*2)) = pk;
        }
      }
    }
  }
  __syncthreads();

  // ---- proj GEMM (idle half): K=512 from regions, kg offset 512 ----
  for (int j8 = 0; j8 < 8; ++j8) {
    #pragma unroll
    for (int kt2 = 0; kt2 < 2; ++kt2) {
      bf16x8 b[4];
      #pragma unroll
      for (int nt = 0; nt < 4; ++nt) {
        const int row = nt*16 + l16, rc = row < 49 ? row : 48;
        b[nt] = *(const bf16x8*)(smem + RG_AT(RGB(j8), rc, (kt2*32 + lk*8)*2));
      }
      const int kg = 512 + j8*64 + kt2*32 + lk*8;
      #pragma unroll
      for (int mt = 0; mt < 2; ++mt) {
        const bf16x8 aw = *(const bf16x8*)(wsc + PJW_OFF + (size_t)(wv*32 + mt*16 + l16)*2048 + kg*2);
        #pragma unroll
        for (int nt = 0; nt < 4; ++nt) pacc[mt][nt] = MFMA(aw, b[nt], pacc[mt][nt]);
      }
    }
  }

  // ---- epilogue: + proj_b + residual, roll(+2,+2) store (R0 fused form) ----
  {
    int xoff[4], roff[4];
    #pragma unroll
    for (int nt = 0; nt < 4; ++nt) {
      const int px = nt*16 + l16;
      const int pc = px < 49 ? px : 48;
      const int gh = (pc/7)*4 + n1, gw = (pc%7)*4 + n2;
      xoff[nt] = gh*28 + gw;
      int rh = gh + 2; if (rh >= 28) rh -= 28;
      int rw = gw + 2; if (rw >= 28) rw -= 28;
      roff[nt] = rh*28 + rw;
    }
    #pragma unroll
    for (int mt = 0; mt < 2; ++mt) {
      #pragma unroll
      for (int r = 0; r < 4; ++r) {
        const int o2 = wv*32 + mt*16 + lk*4 + r;
        const float pb = proj_b[o2];
        const size_t cb = xbase + (size_t)o2*784;
        #pragma unroll
        for (int nt = 0; nt < 4; ++nt) {
          if (nt*16 + l16 < 49)
            out[cb + roff[nt]] = x[cb + xoff[nt]] + pacc[mt][nt][r] + pb;
        }
      }
    }
  }
}

extern "C" void kernel_launch(void* const* d_in, const int* in_sizes, int n_in,
                              void* d_out, int out_size, void* d_ws, size_t ws_size,
                              hipStream_t stream) {
  const float* x      = (const float*)d_in[0];
  const float* pre_w  = (const float*)d_in[1];
  const float* pre_b  = (const float*)d_in[2];
  const float* qk_w   = (const float*)d_in[3];
  const float* qk_b   = (const float*)d_in[4];
  const float* v_w    = (const float*)d_in[5];
  const float* v_b    = (const float*)d_in[6];
  const float* post_w = (const float*)d_in[7];
  const float* post_b = (const float*)d_in[8];
  const float* proj_w = (const float*)d_in[9];
  const float* proj_b = (const float*)d_in[10];
  const float* rpb    = (const float*)d_in[11];
  float* outp = (float*)d_out;
  char* wsc = (char*)d_ws;

  hipFuncSetAttribute((const void*)emo_main, hipFuncAttributeMaxDynamicSharedMemorySize, 81920);

  emo_prep_wb<<<2688, 256, 0, stream>>>(qk_w, v_w, proj_w, rpb,
                                        (unsigned short*)wsc, (float*)(wsc + BIAS_OFF));
  emo_prep_x<<<dim3(25, 64), 256, 0, stream>>>(x, pre_w, pre_b,
                                               (unsigned short*)(wsc + XT_OFF));
  emo_main<<<1024, 512, 76288, stream>>>(x, qk_b, v_b, post_w, post_b, proj_b,
                                         (const char*)wsc, outp);
}

// Round 10
// 286.828 us; speedup vs baseline: 1.2301x; 1.0591x over previous
//
#include <hip/hip_runtime.h>
#include <hip/hip_bf16.h>

typedef __bf16          bf16x8 __attribute__((ext_vector_type(8)));
typedef float           f32x4  __attribute__((ext_vector_type(4)));
typedef unsigned int    u32x2  __attribute__((ext_vector_type(2)));
typedef unsigned int    u32x4v __attribute__((ext_vector_type(4)));

// d_ws layout (bytes)
#define QKW_OFF  0           // 512*256 bf16                        (262144)
#define VW_OFF   262144      // 1024*256 bf16                       (524288)
#define PJW_OFF  786432      // 256*1024 bf16                       (524288)
#define BIAS_OFF 1310720     // [16 win][8 h][16 chunk][64 lane][4 r] f32 (2097152)
#define XT_OFF   70516736    // [64 b][16 win][49 px][256 c] bf16   (25690112)

#define MFMA(a,b,c) __builtin_amdgcn_mfma_f32_16x16x32_bf16((a),(b),(c),0,0,0)
#define ZERO4 ((f32x4){0.f,0.f,0.f,0.f})
#define CBAR() asm volatile("" ::: "memory")
#define PRIO(n) __builtin_amdgcn_s_setprio(n)

// LDS map (76288 B):
//   [0, 25088)        sXN [49 px][256 c] bf16, row 512 B, swz ^((row&7)<<4)
//   [25088, 76288)    8 regions of 6400 B (50*128, 128-aligned bases):
//                     per-wave scratch during attention (q/k -> P -> va),
//                     then out[49 q][64 ch] row 128 B; also idle-v scratch.
// STRUCTURE NOTE (R8/R9 lessons): this kernel sits on a register-allocation
// cliff at the 128 reg/wave budget (launch_bounds(512,4) x 2 blocks/CU).
// Restructuring the post-attention phases (idle-v merge, wider accumulators,
// full unroll) tips it into scratch spills (+70..+220 MB WRITE). Do not widen
// any accumulator live range; SC-overlay idle-v structure is load-bearing.
#define SXN_AT(row, byte)      ((((row)*512 + (byte))) ^ ((((row)&7))<<4))
#define RGB(j)                 (25088 + (j)*6400)
#define RG_AT(base, row, byte) (((base) + (row)*128 + (byte)) ^ (((row)&7)<<4))
#define SC_AT(row, byte)       ((25088 + (row)*512 + (byte)) ^ (((row)&7)<<4))

static __device__ __forceinline__ unsigned cvtpk(float lo, float hi){
  unsigned r;
  asm("v_cvt_pk_bf16_f32 %0, %1, %2" : "=v"(r) : "v"(lo), "v"(hi));
  return r;
}
static __device__ __forceinline__ unsigned short f2bu(float f) {
  unsigned u = __builtin_bit_cast(unsigned, f);
  return (unsigned short)((u + 0x7FFFu + ((u >> 16) & 1u)) >> 16);
}
static __device__ __forceinline__ float gelu_f(float v){
  // v * sigmoid(1.5957691*v*(1+0.044715 v^2)) == tanh-form gelu, |err| < ~1e-3
  return v / (1.f + __expf(-1.5957691216057308f*v*(1.f + 0.044715f*v*v)));
}

// ---------------- prep: weights->bf16 AND bias table, merged (one launch) ----------------
// blocks [0,2560): weight convert; blocks [2560,2688): bias table.
__global__ void emo_prep_wb(const float* __restrict__ qk_w, const float* __restrict__ v_w,
                            const float* __restrict__ proj_w, const float* __restrict__ rpb,
                            unsigned short* __restrict__ w16, float* __restrict__ bx) {
  const int blk = blockIdx.x;
  if (blk < 2560) {
    int i = blk * 256 + threadIdx.x;
    if (i >= 655360) return;
    float v;
    if (i < 131072)      v = qk_w[i];
    else if (i < 393216) v = v_w[i - 131072];
    else                 v = proj_w[i - 393216];
    unsigned u = __builtin_bit_cast(unsigned, v);
    w16[i] = (unsigned short)((u + 0x7FFFu + ((u >> 16) & 1u)) >> 16);
  } else {
    const int wh = blk - 2560;          // win*8 + h
    const int win = wh >> 3, h = wh & 7;
    for (int e = threadIdx.x; e < 4096; e += 256) {
      const int chunk = e >> 8, lane = (e >> 2) & 63, r = e & 3;
      const int mt = chunk >> 2, nt = chunk & 3;
      const int m = mt*16 + (lane >> 4)*4 + r;   // query pixel
      const int n = nt*16 + (lane & 15);         // key pixel
      float v;
      if (n >= 49)      v = -1e30f;              // softmax mask over key dim
      else if (m >= 49) v = 0.f;
      else {
        const int dI = m/7 - n/7 + 6;
        const int dJ = m%7 - n%7 + 6;
        v = rpb[(win*169 + dI*13 + dJ)*8 + h];
      }
      bx[wh*4096 + e] = v;
    }
  }
}

// ---------------- prep: pre-LN + window transform, NCHW f32 -> [b][win][px][c] bf16 ----------------
// block = (chunk of 32 px, b). Static 35 KB LDS -> 4 blocks/CU.
__global__ __launch_bounds__(256)
void emo_prep_x(const float* __restrict__ x, const float* __restrict__ pre_w,
                const float* __restrict__ pre_b, unsigned short* __restrict__ xt) {
  __shared__ float lv[32*257];     // 32896 B
  __shared__ float ps1[8][32];
  __shared__ float ps2[8][32];
  const int tid = threadIdx.x, lane = tid & 63, wv = tid >> 6;
  const int l32 = lane & 31, hp = lane >> 5;
  const int chunk = blockIdx.x, b = blockIdx.y;
  const int s = chunk*32 + l32;            // spatial index h*28+w
  const bool ok = s < 784;
  const float* xb = x + (size_t)b*200704;  // 256*784
  float s1 = 0.f, s2 = 0.f;
  const int c0 = wv*64 + hp*32;
  for (int ci = 0; ci < 32; ++ci) {
    const int c = c0 + ci;
    const float v = ok ? xb[c*784 + s] : 0.f;
    lv[l32*257 + c] = v;
    s1 += v; s2 += v*v;
  }
  ps1[wv*2 + hp][l32] = s1;
  ps2[wv*2 + hp][l32] = s2;
  __syncthreads();
  const int px = tid & 31, j = tid >> 5;
  const int sp = chunk*32 + px;
  if (sp < 784) {
    float t1 = 0.f, t2 = 0.f;
    #pragma unroll
    for (int k = 0; k < 8; ++k) { t1 += ps1[k][px]; t2 += ps2[k][px]; }
    const float mu = t1*(1.f/256.f);
    const float rs = rsqrtf(t2*(1.f/256.f) - mu*mu + 1e-5f);
    const int h = sp/28, w = sp - h*28;
    const int win = (h & 3)*4 + (w & 3);         // n1*4 + n2
    const int wpx = (h >> 2)*7 + (w >> 2);       // ph*7 + pw
    unsigned short* row = xt + (((size_t)b*16 + win)*49 + wpx)*256 + j*32;
    #pragma unroll
    for (int g = 0; g < 4; ++g) {
      float gg[8];
      #pragma unroll
      for (int i2 = 0; i2 < 8; ++i2) {
        const int c = j*32 + g*8 + i2;
        gg[i2] = (lv[px*257 + c] - mu)*rs*pre_w[c] + pre_b[c];
      }
      u32x4v pk = { cvtpk(gg[0],gg[1]), cvtpk(gg[2],gg[3]), cvtpk(gg[4],gg[5]), cvtpk(gg[6],gg[7]) };
      *(u32x4v*)(row + g*8) = pk;
    }
  }
}

// ---------------- main fused kernel (R7 structure, verified best: 290.1 us total) ----------------
// Input path: coalesced xt read. Output: fused residual+roll store (needs R0's
// batch-grouped mapping for L2 write-merging of interleaved window lines — R6 lesson).
// ONLY change vs R7: s_setprio(1)/(0) around MFMA clusters. 2 independent blocks/CU
// drift to different phases -> scheduler can favor the MFMA-issuing wave (T5's
// positive regime; adds zero registers, zero memory ops -> spill cliff untouched).
__global__ __launch_bounds__(512, 4)
void emo_main(const float* __restrict__ x,
              const float* __restrict__ qk_b,  const float* __restrict__ v_b,
              const float* __restrict__ post_w,const float* __restrict__ post_b,
              const float* __restrict__ proj_b,
              const char*  __restrict__ wsc,
              float* __restrict__ out)
{
  extern __shared__ char smem[];
  const int tid  = threadIdx.x;
  const int lane = tid & 63;
  const int l16  = lane & 15;
  const int lk   = lane >> 4;
  const int wv   = tid >> 6;                 // wave = head
  const int bid  = blockIdx.x;
  const int Bi   = (bid & 7) * 8 + (bid >> 7);   // XCD swizzle (bijective, R0 form)
  const int win  = (bid >> 3) & 15;
  const int n1   = win >> 2, n2 = win & 3;
  const size_t xbase = (size_t)Bi * (256*784);
  const int SCR  = RGB(wv);                  // per-wave scratch base

  // ---- stage A: coalesced copy xt[b][win][px][c] -> sXN (swizzled) ----
  {
    const unsigned short* xw = (const unsigned short*)(wsc + XT_OFF)
                             + ((size_t)Bi*16 + win)*(49*256);
    for (int p = wv; p < 49; p += 8) {
      const u32x2 d = *(const u32x2*)(xw + p*256 + lane*4);
      *(u32x2*)(smem + SXN_AT(p, lane*8)) = d;
    }
  }
  __syncthreads();

  // ---- qk GEMM: aq/ak = D[d][px] C-frags ----
  f32x4 aq[2][4], ak[2][4];
  #pragma unroll
  for (int mt = 0; mt < 2; ++mt)
    #pragma unroll
    for (int nt = 0; nt < 4; ++nt) { aq[mt][nt] = ZERO4; ak[mt][nt] = ZERO4; }
  #pragma unroll 2
  for (int kt = 0; kt < 8; ++kt) {
    bf16x8 bx[4];
    #pragma unroll
    for (int nt = 0; nt < 4; ++nt) {
      const int row = nt*16 + l16, rc = row < 49 ? row : 48;
      bx[nt] = *(const bf16x8*)(smem + SXN_AT(rc, kt*64 + lk*16));
    }
    #pragma unroll
    for (int mt = 0; mt < 2; ++mt) {
      const bf16x8 awq = *(const bf16x8*)(wsc + QKW_OFF + (size_t)(      wv*32 + mt*16 + l16)*512 + kt*64 + lk*16);
      const bf16x8 awk = *(const bf16x8*)(wsc + QKW_OFF + (size_t)(256 + wv*32 + mt*16 + l16)*512 + kt*64 + lk*16);
      PRIO(1);
      #pragma unroll
      for (int nt = 0; nt < 4; ++nt) {
        aq[mt][nt] = MFMA(awq, bx[nt], aq[mt][nt]);
        ak[mt][nt] = MFMA(awk, bx[nt], ak[mt][nt]);
      }
      PRIO(0);
    }
  }
  { // + qk bias (per d row)
    const f32x4 bq0 = *(const f32x4*)(qk_b +       wv*32 +      lk*4);
    const f32x4 bq1 = *(const f32x4*)(qk_b +       wv*32 + 16 + lk*4);
    const f32x4 bk0 = *(const f32x4*)(qk_b + 256 + wv*32 +      lk*4);
    const f32x4 bk1 = *(const f32x4*)(qk_b + 256 + wv*32 + 16 + lk*4);
    #pragma unroll
    for (int nt = 0; nt < 4; ++nt) {
      aq[0][nt] += bq0; aq[1][nt] += bq1; ak[0][nt] += bk0; ak[1][nt] += bk1;
    }
  }

  // ---- spill q/k to scratch [px][ q: bytes 0..63 | k: bytes 64..127 ], rows 0..48 ----
  #pragma unroll
  for (int nt = 0; nt < 4; ++nt) {
    const int px = nt*16 + l16;
    if (px < 49) {
      #pragma unroll
      for (int mt = 0; mt < 2; ++mt) {
        u32x2 pq  = { cvtpk(aq[mt][nt][0], aq[mt][nt][1]), cvtpk(aq[mt][nt][2], aq[mt][nt][3]) };
        u32x2 pk2 = { cvtpk(ak[mt][nt][0], ak[mt][nt][1]), cvtpk(ak[mt][nt][2], ak[mt][nt][3]) };
        *(u32x2*)(smem + RG_AT(SCR, px,      (mt*16 + lk*4)*2)) = pq;
        *(u32x2*)(smem + RG_AT(SCR, px, 64 + (mt*16 + lk*4)*2)) = pk2;
      }
    }
  }
  CBAR();

  // ---- reload q/k as A/B fragments (round-2 pinned pattern) ----
  bf16x8 qa[4], kb[4];
  #pragma unroll
  for (int t = 0; t < 4; ++t) {
    const int row = t*16 + l16, rc = row < 49 ? row : 48;
    qa[t] = *(const bf16x8*)(smem + RG_AT(SCR, rc,      lk*16));
    kb[t] = *(const bf16x8*)(smem + RG_AT(SCR, rc, 64 + lk*16));
  }

  // ---- QK^T: S[q][k] + bias (round-2 orientation) ----
  f32x4 s[4][4];
  {
    const float scale = 0.17677669529663689f;
    const float* bxp = (const float*)(wsc + BIAS_OFF) + (size_t)(win*8 + wv)*4096 + lane*4;
    PRIO(1);
    #pragma unroll
    for (int mt = 0; mt < 4; ++mt)
      #pragma unroll
      for (int nt = 0; nt < 4; ++nt) {
        f32x4 z = MFMA(qa[mt], kb[nt], ZERO4);
        s[mt][nt] = z*scale + *(const f32x4*)(bxp + (mt*4 + nt)*256);
      }
    PRIO(0);
  }
  // ---- softmax over k (nt regs + l16 lanes) for each q-row (mt, r) ----
  #pragma unroll
  for (int mt = 0; mt < 4; ++mt) {
    #pragma unroll
    for (int r = 0; r < 4; ++r) {
      float mx = fmaxf(fmaxf(s[mt][0][r], s[mt][1][r]), fmaxf(s[mt][2][r], s[mt][3][r]));
      mx = fmaxf(mx, __shfl_xor(mx, 1)); mx = fmaxf(mx, __shfl_xor(mx, 2));
      mx = fmaxf(mx, __shfl_xor(mx, 4)); mx = fmaxf(mx, __shfl_xor(mx, 8));
      const float e0 = __expf(s[mt][0][r]-mx), e1 = __expf(s[mt][1][r]-mx);
      const float e2 = __expf(s[mt][2][r]-mx), e3 = __expf(s[mt][3][r]-mx);
      float sm = e0+e1+e2+e3;
      sm += __shfl_xor(sm, 1); sm += __shfl_xor(sm, 2);
      sm += __shfl_xor(sm, 4); sm += __shfl_xor(sm, 8);
      const float inv = 1.f/sm;
      s[mt][0][r] = e0*inv; s[mt][1][r] = e1*inv;
      s[mt][2][r] = e2*inv; s[mt][3][r] = e3*inv;
    }
  }
  // ---- store P [q][k] rows 0..48 (all 64 k cols; masked cols are exactly 0) ----
  #pragma unroll
  for (int mt = 0; mt < 4; ++mt)
    #pragma unroll
    for (int r = 0; r < 4; ++r) {
      const int q = mt*16 + lk*4 + r;
      if (q < 49) {
        #pragma unroll
        for (int nt = 0; nt < 4; ++nt)
          *(unsigned short*)(smem + RG_AT(SCR, q, (nt*16 + l16)*2)) = f2bu(s[mt][nt][r]);
      }
    }
  CBAR();

  // ---- va GEMM: av = D[px][ch] C-frags ----
  f32x4 av[4][4];
  #pragma unroll
  for (int mt = 0; mt < 4; ++mt)
    #pragma unroll
    for (int nt = 0; nt < 4; ++nt) av[mt][nt] = ZERO4;
  #pragma unroll 2
  for (int kt = 0; kt < 8; ++kt) {
    bf16x8 ax[4], bw[4];
    #pragma unroll
    for (int t = 0; t < 4; ++t) {
      const int row = t*16 + l16, rc = row < 49 ? row : 48;
      ax[t] = *(const bf16x8*)(smem + SXN_AT(rc, kt*64 + lk*16));
      bw[t] = *(const bf16x8*)(wsc + VW_OFF + (size_t)(wv*64 + t*16 + l16)*512 + kt*64 + lk*16);
    }
    PRIO(1);
    #pragma unroll
    for (int mt = 0; mt < 4; ++mt)
      #pragma unroll
      for (int nt = 0; nt < 4; ++nt) av[mt][nt] = MFMA(ax[mt], bw[nt], av[mt][nt]);
    PRIO(0);
  }
  { // + v bias (per ch col)
    #pragma unroll
    for (int nt = 0; nt < 4; ++nt) {
      const float vb = v_b[wv*64 + nt*16 + l16];
      #pragma unroll
      for (int mt = 0; mt < 4; ++mt)
        #pragma unroll
        for (int r = 0; r < 4; ++r) av[mt][nt][r] += vb;
    }
  }

  // ---- read P as B-frags (round-2 pinned pattern) ----
  bf16x8 fpb[4][2];
  #pragma unroll
  for (int t = 0; t < 4; ++t) {
    const int row = t*16 + l16, rc = row < 49 ? row : 48;
    #pragma unroll
    for (int kt = 0; kt < 2; ++kt)
      fpb[t][kt] = *(const bf16x8*)(smem + RG_AT(SCR, rc, (kt*32 + lk*8)*2));
  }
  CBAR();

  // ---- PV in two 32-ch halves through scratch [ch][px] (rows 0..31) ----
  f32x4 o[4][4];
  #pragma unroll
  for (int h2 = 0; h2 < 2; ++h2) {
    #pragma unroll
    for (int tc = 0; tc < 2; ++tc) {
      const int nt = h2*2 + tc;          // global ch tile
      const int chrow = tc*16 + l16;     // row within this half
      #pragma unroll
      for (int mt = 0; mt < 4; ++mt) {
        u32x2 pv = { cvtpk(av[mt][nt][0], av[mt][nt][1]), cvtpk(av[mt][nt][2], av[mt][nt][3]) };
        *(u32x2*)(smem + RG_AT(SCR, chrow, (mt*16 + lk*4)*2)) = pv;
      }
    }
    CBAR();
    #pragma unroll
    for (int tc = 0; tc < 2; ++tc) {
      const int mtc = h2*2 + tc;
      const bf16x8 a0 = *(const bf16x8*)(smem + RG_AT(SCR, tc*16 + l16, (     lk*8)*2));
      const bf16x8 a1 = *(const bf16x8*)(smem + RG_AT(SCR, tc*16 + l16, (32 + lk*8)*2));
      PRIO(1);
      #pragma unroll
      for (int nt = 0; nt < 4; ++nt) {
        f32x4 z = MFMA(a0, fpb[nt][0], ZERO4);
        o[mtc][nt] = MFMA(a1, fpb[nt][1], z);
      }
      PRIO(0);
    }
    CBAR();
  }

  // ---- store attention out [q][ch] into region wv ----
  #pragma unroll
  for (int mtc = 0; mtc < 4; ++mtc)
    #pragma unroll
    for (int nt = 0; nt < 4; ++nt) {
      const int q = nt*16 + l16;
      if (q < 49) {
        u32x2 pk = { cvtpk(o[mtc][nt][0], o[mtc][nt][1]), cvtpk(o[mtc][nt][2], o[mtc][nt][3]) };
        *(u32x2*)(smem + RG_AT(RGB(wv), q, (mtc*16 + lk*4)*2)) = pk;
      }
    }
  __syncthreads();

  // ---- post-LN (512 ch) + gelu, in place on regions ----
  {
    const int px = tid >> 3, j = tid & 7;
    if (px < 49) {
      bf16x8 f[8];
      float s1 = 0.f, s2 = 0.f;
      #pragma unroll
      for (int c8 = 0; c8 < 8; ++c8) {
        f[c8] = *(const bf16x8*)(smem + RG_AT(RGB(j), px, c8*16));
        #pragma unroll
        for (int i = 0; i < 8; ++i) { const float v = (float)f[c8][i]; s1 += v; s2 += v*v; }
      }
      s1 += __shfl_xor(s1, 1); s1 += __shfl_xor(s1, 2); s1 += __shfl_xor(s1, 4);
      s2 += __shfl_xor(s2, 1); s2 += __shfl_xor(s2, 2); s2 += __shfl_xor(s2, 4);
      const float mu = s1*(1.f/512.f);
      const float rs = rsqrtf(s2*(1.f/512.f) - mu*mu + 1e-5f);
      #pragma unroll
      for (int c8 = 0; c8 < 8; ++c8) {
        const f32x4 pw0 = *(const f32x4*)(post_w + j*64 + c8*8);
        const f32x4 pw1 = *(const f32x4*)(post_w + j*64 + c8*8 + 4);
        const f32x4 pb0 = *(const f32x4*)(post_b + j*64 + c8*8);
        const f32x4 pb1 = *(const f32x4*)(post_b + j*64 + c8*8 + 4);
        float g[8];
        #pragma unroll
        for (int i = 0; i < 8; ++i) {
          const float v = (float)f[c8][i];
          const float w = i < 4 ? pw0[i] : pw1[i-4];
          const float b = i < 4 ? pb0[i] : pb1[i-4];
          g[i] = gelu_f((v-mu)*rs*w + b);
        }
        u32x4v pk = { cvtpk(g[0],g[1]), cvtpk(g[2],g[3]), cvtpk(g[4],g[5]), cvtpk(g[6],g[7]) };
        *(u32x4v*)(smem + RG_AT(RGB(j), px, c8*16)) = pk;
      }
    }
  }
  __syncthreads();

  // ---- proj GEMM: D[o][px], K=1024 (attn half from regions) ----
  f32x4 pacc[2][4];
  #pragma unroll
  for (int mt = 0; mt < 2; ++mt)
    #pragma unroll
    for (int nt = 0; nt < 4; ++nt) pacc[mt][nt] = ZERO4;
  for (int j8 = 0; j8 < 8; ++j8) {
    #pragma unroll
    for (int kt2 = 0; kt2 < 2; ++kt2) {
      bf16x8 b[4];
      #pragma unroll
      for (int nt = 0; nt < 4; ++nt) {
        const int row = nt*16 + l16, rc = row < 49 ? row : 48;
        b[nt] = *(const bf16x8*)(smem + RG_AT(RGB(j8), rc, (kt2*32 + lk*8)*2));
      }
      const int kg = j8*64 + kt2*32 + lk*8;
      #pragma unroll
      for (int mt = 0; mt < 2; ++mt) {
        const bf16x8 aw = *(const bf16x8*)(wsc + PJW_OFF + (size_t)(wv*32 + mt*16 + l16)*2048 + kg*2);
        PRIO(1);
        #pragma unroll
        for (int nt = 0; nt < 4; ++nt) pacc[mt][nt] = MFMA(aw, b[nt], pacc[mt][nt]);
        PRIO(0);
      }
    }
  }
  // idle half: 2 chunks of 256 ch through scratch overlay [64 px][256 c]
  for (int half = 0; half < 2; ++half) {
    __syncthreads();
    f32x4 ia[2][4];
    #pragma unroll
    for (int mt = 0; mt < 2; ++mt)
      #pragma unroll
      for (int nt = 0; nt < 4; ++nt) ia[mt][nt] = ZERO4;
    const int r0 = 512 + half*256 + wv*32;
    #pragma unroll 2
    for (int kt = 0; kt < 8; ++kt) {
      bf16x8 b[4];
      #pragma unroll
      for (int nt = 0; nt < 4; ++nt) {
        const int row = nt*16 + l16, rc = row < 49 ? row : 48;
        b[nt] = *(const bf16x8*)(smem + SXN_AT(rc, kt*64 + lk*16));
      }
      #pragma unroll
      for (int mt = 0; mt < 2; ++mt) {
        const bf16x8 aw = *(const bf16x8*)(wsc + VW_OFF + (size_t)(r0 + mt*16 + l16)*512 + kt*64 + lk*16);
        PRIO(1);
        #pragma unroll
        for (int nt = 0; nt < 4; ++nt) ia[mt][nt] = MFMA(aw, b[nt], ia[mt][nt]);
        PRIO(0);
      }
    }
    #pragma unroll
    for (int mt = 0; mt < 2; ++mt) {
      const f32x4 vb = *(const f32x4*)(v_b + r0 + mt*16 + lk*4);
      #pragma unroll
      for (int nt = 0; nt < 4; ++nt) {
        const int px = nt*16 + l16;
        const int chl = wv*32 + mt*16 + lk*4;
        u32x2 pk = { cvtpk(gelu_f(ia[mt][nt][0]+vb[0]), gelu_f(ia[mt][nt][1]+vb[1])),
                     cvtpk(gelu_f(ia[mt][nt][2]+vb[2]), gelu_f(ia[mt][nt][3]+vb[3])) };
        *(u32x2*)(smem + SC_AT(px, chl*2)) = pk;
      }
    }
    __syncthreads();
    #pragma unroll 2
    for (int kt = 0; kt < 8; ++kt) {
      bf16x8 b[4];
      #pragma unroll
      for (int nt = 0; nt < 4; ++nt) {
        const int row = nt*16 + l16;
        b[nt] = *(const bf16x8*)(smem + SC_AT(row, (kt*32 + lk*8)*2));
      }
      const int kg = 512 + half*256 + kt*32 + lk*8;
      #pragma unroll
      for (int mt = 0; mt < 2; ++mt) {
        const bf16x8 aw = *(const bf16x8*)(wsc + PJW_OFF + (size_t)(wv*32 + mt*16 + l16)*2048 + kg*2);
        PRIO(1);
        #pragma unroll
        for (int nt = 0; nt < 4; ++nt) pacc[mt][nt] = MFMA(aw, b[nt], pacc[mt][nt]);
        PRIO(0);
      }
    }
  }

  // ---- epilogue: + proj_b + residual, roll(+2,+2) store (R0 fused form) ----
  {
    int xoff[4], roff[4];
    #pragma unroll
    for (int nt = 0; nt < 4; ++nt) {
      const int px = nt*16 + l16;
      const int pc = px < 49 ? px : 48;
      const int gh = (pc/7)*4 + n1, gw = (pc%7)*4 + n2;
      xoff[nt] = gh*28 + gw;
      int rh = gh + 2; if (rh >= 28) rh -= 28;
      int rw = gw + 2; if (rw >= 28) rw -= 28;
      roff[nt] = rh*28 + rw;
    }
    #pragma unroll
    for (int mt = 0; mt < 2; ++mt) {
      #pragma unroll
      for (int r = 0; r < 4; ++r) {
        const int o2 = wv*32 + mt*16 + lk*4 + r;
        const float pb = proj_b[o2];
        const size_t cb = xbase + (size_t)o2*784;
        #pragma unroll
        for (int nt = 0; nt < 4; ++nt) {
          if (nt*16 + l16 < 49)
            out[cb + roff[nt]] = x[cb + xoff[nt]] + pacc[mt][nt][r] + pb;
        }
      }
    }
  }
}

extern "C" void kernel_launch(void* const* d_in, const int* in_sizes, int n_in,
                              void* d_out, int out_size, void* d_ws, size_t ws_size,
                              hipStream_t stream) {
  const float* x      = (const float*)d_in[0];
  const float* pre_w  = (const float*)d_in[1];
  const float* pre_b  = (const float*)d_in[2];
  const float* qk_w   = (const float*)d_in[3];
  const float* qk_b   = (const float*)d_in[4];
  const float* v_w    = (const float*)d_in[5];
  const float* v_b    = (const float*)d_in[6];
  const float* post_w = (const float*)d_in[7];
  const float* post_b = (const float*)d_in[8];
  const float* proj_w = (const float*)d_in[9];
  const float* proj_b = (const float*)d_in[10];
  const float* rpb    = (const float*)d_in[11];
  float* outp = (float*)d_out;
  char* wsc = (char*)d_ws;

  hipFuncSetAttribute((const void*)emo_main, hipFuncAttributeMaxDynamicSharedMemorySize, 81920);

  emo_prep_wb<<<2688, 256, 0, stream>>>(qk_w, v_w, proj_w, rpb,
                                        (unsigned short*)wsc, (float*)(wsc + BIAS_OFF));
  emo_prep_x<<<dim3(25, 64), 256, 0, stream>>>(x, pre_w, pre_b,
                                               (unsigned short*)(wsc + XT_OFF));
  emo_main<<<1024, 512, 76288, stream>>>(x, qk_b, v_b, post_w, post_b, proj_b,
                                         (const char*)wsc, outp);
}

// Round 11
// 283.791 us; speedup vs baseline: 1.2432x; 1.0107x over previous
//
#include <hip/hip_runtime.h>
#include <hip/hip_bf16.h>

typedef __bf16          bf16x8 __attribute__((ext_vector_type(8)));
typedef float           f32x4  __attribute__((ext_vector_type(4)));
typedef unsigned int    u32x2  __attribute__((ext_vector_type(2)));
typedef unsigned int    u32x4v __attribute__((ext_vector_type(4)));

// d_ws layout (bytes)
#define QKW_OFF  0           // 512*256 bf16                        (262144)
#define VW_OFF   262144      // 1024*256 bf16                       (524288)
#define PJW_OFF  786432      // 256*1024 bf16                       (524288)
#define BIAS_OFF 1310720     // [16 win][8 h][16 chunk][64 lane][4 r] f32 (2097152)
#define XT_OFF   70516736    // [64 b][16 win][49 px][256 c] bf16   (25690112)

#define MFMA(a,b,c) __builtin_amdgcn_mfma_f32_16x16x32_bf16((a),(b),(c),0,0,0)
#define ZERO4 ((f32x4){0.f,0.f,0.f,0.f})
#define CBAR() asm volatile("" ::: "memory")
#define PRIO(n) __builtin_amdgcn_s_setprio(n)

// LDS map (76288 B):
//   [0, 25088)        sXN [49 px][256 c] bf16, row 512 B, swz ^((row&7)<<4)
//   [25088, 76288)    8 regions of 6400 B (50*128, 128-aligned bases):
//                     per-wave scratch during attention (q/k -> P -> va),
//                     then out[49 q][64 ch] row 128 B; also idle-v scratch.
// STRUCTURE NOTE (R8/R9 lessons): this kernel sits on a register-allocation
// cliff at the 128 reg/wave budget (launch_bounds(512,4) x 2 blocks/CU).
// Restructuring the post-attention phases (idle-v merge, wider accumulators,
// full unroll) tips it into scratch spills (+70..+220 MB WRITE). Do not widen
// any accumulator live range; SC-overlay idle-v structure is load-bearing.
// Block mapping must stay batch-grouped (R6: win-pinned swizzle breaks the
// fused epilogue's L2 write-merging of interleaved window lines).
#define SXN_AT(row, byte)      ((((row)*512 + (byte))) ^ ((((row)&7))<<4))
#define RGB(j)                 (25088 + (j)*6400)
#define RG_AT(base, row, byte) (((base) + (row)*128 + (byte)) ^ (((row)&7)<<4))
#define SC_AT(row, byte)       ((25088 + (row)*512 + (byte)) ^ (((row)&7)<<4))

static __device__ __forceinline__ unsigned cvtpk(float lo, float hi){
  unsigned r;
  asm("v_cvt_pk_bf16_f32 %0, %1, %2" : "=v"(r) : "v"(lo), "v"(hi));
  return r;
}
static __device__ __forceinline__ unsigned short f2bu(float f) {
  unsigned u = __builtin_bit_cast(unsigned, f);
  return (unsigned short)((u + 0x7FFFu + ((u >> 16) & 1u)) >> 16);
}
static __device__ __forceinline__ float gelu_f(float v){
  // v * sigmoid(1.5957691*v*(1+0.044715 v^2)) == tanh-form gelu, |err| < ~1e-3
  return v / (1.f + __expf(-1.5957691216057308f*v*(1.f + 0.044715f*v*v)));
}

// ---------------- prep (single launch): pre-LN/window transform + weights + bias ----------------
// blocks [0,1600): pre-LN + NCHW->xt window transform (chunk = blk%25, b = blk/25)
// blocks [1600,4160): weight fp32->bf16 convert
// blocks [4160,4288): bias table build
__global__ __launch_bounds__(256)
void emo_prep(const float* __restrict__ x, const float* __restrict__ pre_w,
              const float* __restrict__ pre_b,
              const float* __restrict__ qk_w, const float* __restrict__ v_w,
              const float* __restrict__ proj_w, const float* __restrict__ rpb,
              unsigned short* __restrict__ xt,
              unsigned short* __restrict__ w16, float* __restrict__ bx) {
  const int blk = blockIdx.x;
  const int tid = threadIdx.x;
  if (blk >= 1600) {
    if (blk < 4160) {          // ---- weight convert ----
      int i = (blk - 1600) * 256 + tid;
      if (i >= 655360) return;
      float v;
      if (i < 131072)      v = qk_w[i];
      else if (i < 393216) v = v_w[i - 131072];
      else                 v = proj_w[i - 393216];
      unsigned u = __builtin_bit_cast(unsigned, v);
      w16[i] = (unsigned short)((u + 0x7FFFu + ((u >> 16) & 1u)) >> 16);
    } else {                   // ---- bias table ----
      const int wh = blk - 4160;          // win*8 + h
      const int win = wh >> 3, h = wh & 7;
      for (int e = tid; e < 4096; e += 256) {
        const int chunk = e >> 8, lane = (e >> 2) & 63, r = e & 3;
        const int mt = chunk >> 2, nt = chunk & 3;
        const int m = mt*16 + (lane >> 4)*4 + r;   // query pixel
        const int n = nt*16 + (lane & 15);         // key pixel
        float v;
        if (n >= 49)      v = -1e30f;              // softmax mask over key dim
        else if (m >= 49) v = 0.f;
        else {
          const int dI = m/7 - n/7 + 6;
          const int dJ = m%7 - n%7 + 6;
          v = rpb[(win*169 + dI*13 + dJ)*8 + h];
        }
        bx[wh*4096 + e] = v;
      }
    }
    return;
  }
  // ---- pre-LN + window transform ----
  __shared__ float lv[32*257];     // 32896 B
  __shared__ float ps1[8][32];
  __shared__ float ps2[8][32];
  const int lane = tid & 63, wv = tid >> 6;
  const int l32 = lane & 31, hp = lane >> 5;
  const int chunk = blk % 25, b = blk / 25;
  const int s = chunk*32 + l32;            // spatial index h*28+w
  const bool ok = s < 784;
  const float* xb = x + (size_t)b*200704;  // 256*784
  float s1 = 0.f, s2 = 0.f;
  const int c0 = wv*64 + hp*32;
  for (int ci = 0; ci < 32; ++ci) {
    const int c = c0 + ci;
    const float v = ok ? xb[c*784 + s] : 0.f;
    lv[l32*257 + c] = v;
    s1 += v; s2 += v*v;
  }
  ps1[wv*2 + hp][l32] = s1;
  ps2[wv*2 + hp][l32] = s2;
  __syncthreads();
  const int px = tid & 31, j = tid >> 5;
  const int sp = chunk*32 + px;
  if (sp < 784) {
    float t1 = 0.f, t2 = 0.f;
    #pragma unroll
    for (int k = 0; k < 8; ++k) { t1 += ps1[k][px]; t2 += ps2[k][px]; }
    const float mu = t1*(1.f/256.f);
    const float rs = rsqrtf(t2*(1.f/256.f) - mu*mu + 1e-5f);
    const int h = sp/28, w = sp - h*28;
    const int win = (h & 3)*4 + (w & 3);         // n1*4 + n2
    const int wpx = (h >> 2)*7 + (w >> 2);       // ph*7 + pw
    unsigned short* row = xt + (((size_t)b*16 + win)*49 + wpx)*256 + j*32;
    #pragma unroll
    for (int g = 0; g < 4; ++g) {
      float gg[8];
      #pragma unroll
      for (int i2 = 0; i2 < 8; ++i2) {
        const int c = j*32 + g*8 + i2;
        gg[i2] = (lv[px*257 + c] - mu)*rs*pre_w[c] + pre_b[c];
      }
      u32x4v pk = { cvtpk(gg[0],gg[1]), cvtpk(gg[2],gg[3]), cvtpk(gg[4],gg[5]), cvtpk(gg[6],gg[7]) };
      *(u32x4v*)(row + g*8) = pk;
    }
  }
}

// ---------------- main fused kernel (R10 structure = verified best, 286.8 us total) ----------------
// Changes vs R10 (both codegen-local): (1) kt=0 qk weight loads hoisted above the
// stage-A barrier — LDS-independent, hides L2/HBM latency at the serial head of
// every block under the xt->LDS copy (+16 VGPRs at minimum live pressure);
// (2) prep launched as one kernel (launch structure only, main untouched).
__global__ __launch_bounds__(512, 4)
void emo_main(const float* __restrict__ x,
              const float* __restrict__ qk_b,  const float* __restrict__ v_b,
              const float* __restrict__ post_w,const float* __restrict__ post_b,
              const float* __restrict__ proj_b,
              const char*  __restrict__ wsc,
              float* __restrict__ out)
{
  extern __shared__ char smem[];
  const int tid  = threadIdx.x;
  const int lane = tid & 63;
  const int l16  = lane & 15;
  const int lk   = lane >> 4;
  const int wv   = tid >> 6;                 // wave = head
  const int bid  = blockIdx.x;
  const int Bi   = (bid & 7) * 8 + (bid >> 7);   // XCD swizzle (bijective, R0 form)
  const int win  = (bid >> 3) & 15;
  const int n1   = win >> 2, n2 = win & 3;
  const size_t xbase = (size_t)Bi * (256*784);
  const int SCR  = RGB(wv);                  // per-wave scratch base

  // ---- prefetch qk weights for kt=0 (LDS-independent; hides latency under stage A) ----
  bf16x8 awq0[2], awk0[2];
  #pragma unroll
  for (int mt = 0; mt < 2; ++mt) {
    awq0[mt] = *(const bf16x8*)(wsc + QKW_OFF + (size_t)(      wv*32 + mt*16 + l16)*512 + lk*16);
    awk0[mt] = *(const bf16x8*)(wsc + QKW_OFF + (size_t)(256 + wv*32 + mt*16 + l16)*512 + lk*16);
  }

  // ---- stage A: coalesced copy xt[b][win][px][c] -> sXN (swizzled) ----
  {
    const unsigned short* xw = (const unsigned short*)(wsc + XT_OFF)
                             + ((size_t)Bi*16 + win)*(49*256);
    for (int p = wv; p < 49; p += 8) {
      const u32x2 d = *(const u32x2*)(xw + p*256 + lane*4);
      *(u32x2*)(smem + SXN_AT(p, lane*8)) = d;
    }
  }
  __syncthreads();

  // ---- qk GEMM: aq/ak = D[d][px] C-frags (kt=0 peeled with prefetched weights) ----
  f32x4 aq[2][4], ak[2][4];
  {
    bf16x8 bx[4];
    #pragma unroll
    for (int nt = 0; nt < 4; ++nt) {
      const int row = nt*16 + l16, rc = row < 49 ? row : 48;
      bx[nt] = *(const bf16x8*)(smem + SXN_AT(rc, lk*16));
    }
    PRIO(1);
    #pragma unroll
    for (int mt = 0; mt < 2; ++mt)
      #pragma unroll
      for (int nt = 0; nt < 4; ++nt) {
        aq[mt][nt] = MFMA(awq0[mt], bx[nt], ZERO4);
        ak[mt][nt] = MFMA(awk0[mt], bx[nt], ZERO4);
      }
    PRIO(0);
  }
  #pragma unroll 2
  for (int kt = 1; kt < 8; ++kt) {
    bf16x8 bx[4];
    #pragma unroll
    for (int nt = 0; nt < 4; ++nt) {
      const int row = nt*16 + l16, rc = row < 49 ? row : 48;
      bx[nt] = *(const bf16x8*)(smem + SXN_AT(rc, kt*64 + lk*16));
    }
    #pragma unroll
    for (int mt = 0; mt < 2; ++mt) {
      const bf16x8 awq = *(const bf16x8*)(wsc + QKW_OFF + (size_t)(      wv*32 + mt*16 + l16)*512 + kt*64 + lk*16);
      const bf16x8 awk = *(const bf16x8*)(wsc + QKW_OFF + (size_t)(256 + wv*32 + mt*16 + l16)*512 + kt*64 + lk*16);
      PRIO(1);
      #pragma unroll
      for (int nt = 0; nt < 4; ++nt) {
        aq[mt][nt] = MFMA(awq, bx[nt], aq[mt][nt]);
        ak[mt][nt] = MFMA(awk, bx[nt], ak[mt][nt]);
      }
      PRIO(0);
    }
  }
  { // + qk bias (per d row)
    const f32x4 bq0 = *(const f32x4*)(qk_b +       wv*32 +      lk*4);
    const f32x4 bq1 = *(const f32x4*)(qk_b +       wv*32 + 16 + lk*4);
    const f32x4 bk0 = *(const f32x4*)(qk_b + 256 + wv*32 +      lk*4);
    const f32x4 bk1 = *(const f32x4*)(qk_b + 256 + wv*32 + 16 + lk*4);
    #pragma unroll
    for (int nt = 0; nt < 4; ++nt) {
      aq[0][nt] += bq0; aq[1][nt] += bq1; ak[0][nt] += bk0; ak[1][nt] += bk1;
    }
  }

  // ---- spill q/k to scratch [px][ q: bytes 0..63 | k: bytes 64..127 ], rows 0..48 ----
  #pragma unroll
  for (int nt = 0; nt < 4; ++nt) {
    const int px = nt*16 + l16;
    if (px < 49) {
      #pragma unroll
      for (int mt = 0; mt < 2; ++mt) {
        u32x2 pq  = { cvtpk(aq[mt][nt][0], aq[mt][nt][1]), cvtpk(aq[mt][nt][2], aq[mt][nt][3]) };
        u32x2 pk2 = { cvtpk(ak[mt][nt][0], ak[mt][nt][1]), cvtpk(ak[mt][nt][2], ak[mt][nt][3]) };
        *(u32x2*)(smem + RG_AT(SCR, px,      (mt*16 + lk*4)*2)) = pq;
        *(u32x2*)(smem + RG_AT(SCR, px, 64 + (mt*16 + lk*4)*2)) = pk2;
      }
    }
  }
  CBAR();

  // ---- reload q/k as A/B fragments (round-2 pinned pattern) ----
  bf16x8 qa[4], kb[4];
  #pragma unroll
  for (int t = 0; t < 4; ++t) {
    const int row = t*16 + l16, rc = row < 49 ? row : 48;
    qa[t] = *(const bf16x8*)(smem + RG_AT(SCR, rc,      lk*16));
    kb[t] = *(const bf16x8*)(smem + RG_AT(SCR, rc, 64 + lk*16));
  }

  // ---- QK^T: S[q][k] + bias (round-2 orientation) ----
  f32x4 s[4][4];
  {
    const float scale = 0.17677669529663689f;
    const float* bxp = (const float*)(wsc + BIAS_OFF) + (size_t)(win*8 + wv)*4096 + lane*4;
    PRIO(1);
    #pragma unroll
    for (int mt = 0; mt < 4; ++mt)
      #pragma unroll
      for (int nt = 0; nt < 4; ++nt) {
        f32x4 z = MFMA(qa[mt], kb[nt], ZERO4);
        s[mt][nt] = z*scale + *(const f32x4*)(bxp + (mt*4 + nt)*256);
      }
    PRIO(0);
  }
  // ---- softmax over k (nt regs + l16 lanes) for each q-row (mt, r) ----
  #pragma unroll
  for (int mt = 0; mt < 4; ++mt) {
    #pragma unroll
    for (int r = 0; r < 4; ++r) {
      float mx = fmaxf(fmaxf(s[mt][0][r], s[mt][1][r]), fmaxf(s[mt][2][r], s[mt][3][r]));
      mx = fmaxf(mx, __shfl_xor(mx, 1)); mx = fmaxf(mx, __shfl_xor(mx, 2));
      mx = fmaxf(mx, __shfl_xor(mx, 4)); mx = fmaxf(mx, __shfl_xor(mx, 8));
      const float e0 = __expf(s[mt][0][r]-mx), e1 = __expf(s[mt][1][r]-mx);
      const float e2 = __expf(s[mt][2][r]-mx), e3 = __expf(s[mt][3][r]-mx);
      float sm = e0+e1+e2+e3;
      sm += __shfl_xor(sm, 1); sm += __shfl_xor(sm, 2);
      sm += __shfl_xor(sm, 4); sm += __shfl_xor(sm, 8);
      const float inv = 1.f/sm;
      s[mt][0][r] = e0*inv; s[mt][1][r] = e1*inv;
      s[mt][2][r] = e2*inv; s[mt][3][r] = e3*inv;
    }
  }
  // ---- store P [q][k] rows 0..48 (all 64 k cols; masked cols are exactly 0) ----
  #pragma unroll
  for (int mt = 0; mt < 4; ++mt)
    #pragma unroll
    for (int r = 0; r < 4; ++r) {
      const int q = mt*16 + lk*4 + r;
      if (q < 49) {
        #pragma unroll
        for (int nt = 0; nt < 4; ++nt)
          *(unsigned short*)(smem + RG_AT(SCR, q, (nt*16 + l16)*2)) = f2bu(s[mt][nt][r]);
      }
    }
  CBAR();

  // ---- va GEMM: av = D[px][ch] C-frags ----
  f32x4 av[4][4];
  #pragma unroll
  for (int mt = 0; mt < 4; ++mt)
    #pragma unroll
    for (int nt = 0; nt < 4; ++nt) av[mt][nt] = ZERO4;
  #pragma unroll 2
  for (int kt = 0; kt < 8; ++kt) {
    bf16x8 ax[4], bw[4];
    #pragma unroll
    for (int t = 0; t < 4; ++t) {
      const int row = t*16 + l16, rc = row < 49 ? row : 48;
      ax[t] = *(const bf16x8*)(smem + SXN_AT(rc, kt*64 + lk*16));
      bw[t] = *(const bf16x8*)(wsc + VW_OFF + (size_t)(wv*64 + t*16 + l16)*512 + kt*64 + lk*16);
    }
    PRIO(1);
    #pragma unroll
    for (int mt = 0; mt < 4; ++mt)
      #pragma unroll
      for (int nt = 0; nt < 4; ++nt) av[mt][nt] = MFMA(ax[mt], bw[nt], av[mt][nt]);
    PRIO(0);
  }
  { // + v bias (per ch col)
    #pragma unroll
    for (int nt = 0; nt < 4; ++nt) {
      const float vb = v_b[wv*64 + nt*16 + l16];
      #pragma unroll
      for (int mt = 0; mt < 4; ++mt)
        #pragma unroll
        for (int r = 0; r < 4; ++r) av[mt][nt][r] += vb;
    }
  }

  // ---- read P as B-frags (round-2 pinned pattern) ----
  bf16x8 fpb[4][2];
  #pragma unroll
  for (int t = 0; t < 4; ++t) {
    const int row = t*16 + l16, rc = row < 49 ? row : 48;
    #pragma unroll
    for (int kt = 0; kt < 2; ++kt)
      fpb[t][kt] = *(const bf16x8*)(smem + RG_AT(SCR, rc, (kt*32 + lk*8)*2));
  }
  CBAR();

  // ---- PV in two 32-ch halves through scratch [ch][px] (rows 0..31) ----
  f32x4 o[4][4];
  #pragma unroll
  for (int h2 = 0; h2 < 2; ++h2) {
    #pragma unroll
    for (int tc = 0; tc < 2; ++tc) {
      const int nt = h2*2 + tc;          // global ch tile
      const int chrow = tc*16 + l16;     // row within this half
      #pragma unroll
      for (int mt = 0; mt < 4; ++mt) {
        u32x2 pv = { cvtpk(av[mt][nt][0], av[mt][nt][1]), cvtpk(av[mt][nt][2], av[mt][nt][3]) };
        *(u32x2*)(smem + RG_AT(SCR, chrow, (mt*16 + lk*4)*2)) = pv;
      }
    }
    CBAR();
    #pragma unroll
    for (int tc = 0; tc < 2; ++tc) {
      const int mtc = h2*2 + tc;
      const bf16x8 a0 = *(const bf16x8*)(smem + RG_AT(SCR, tc*16 + l16, (     lk*8)*2));
      const bf16x8 a1 = *(const bf16x8*)(smem + RG_AT(SCR, tc*16 + l16, (32 + lk*8)*2));
      PRIO(1);
      #pragma unroll
      for (int nt = 0; nt < 4; ++nt) {
        f32x4 z = MFMA(a0, fpb[nt][0], ZERO4);
        o[mtc][nt] = MFMA(a1, fpb[nt][1], z);
      }
      PRIO(0);
    }
    CBAR();
  }

  // ---- store attention out [q][ch] into region wv ----
  #pragma unroll
  for (int mtc = 0; mtc < 4; ++mtc)
    #pragma unroll
    for (int nt = 0; nt < 4; ++nt) {
      const int q = nt*16 + l16;
      if (q < 49) {
        u32x2 pk = { cvtpk(o[mtc][nt][0], o[mtc][nt][1]), cvtpk(o[mtc][nt][2], o[mtc][nt][3]) };
        *(u32x2*)(smem + RG_AT(RGB(wv), q, (mtc*16 + lk*4)*2)) = pk;
      }
    }
  __syncthreads();

  // ---- post-LN (512 ch) + gelu, in place on regions ----
  {
    const int px = tid >> 3, j = tid & 7;
    if (px < 49) {
      bf16x8 f[8];
      float s1 = 0.f, s2 = 0.f;
      #pragma unroll
      for (int c8 = 0; c8 < 8; ++c8) {
        f[c8] = *(const bf16x8*)(smem + RG_AT(RGB(j), px, c8*16));
        #pragma unroll
        for (int i = 0; i < 8; ++i) { const float v = (float)f[c8][i]; s1 += v; s2 += v*v; }
      }
      s1 += __shfl_xor(s1, 1); s1 += __shfl_xor(s1, 2); s1 += __shfl_xor(s1, 4);
      s2 += __shfl_xor(s2, 1); s2 += __shfl_xor(s2, 2); s2 += __shfl_xor(s2, 4);
      const float mu = s1*(1.f/512.f);
      const float rs = rsqrtf(s2*(1.f/512.f) - mu*mu + 1e-5f);
      #pragma unroll
      for (int c8 = 0; c8 < 8; ++c8) {
        const f32x4 pw0 = *(const f32x4*)(post_w + j*64 + c8*8);
        const f32x4 pw1 = *(const f32x4*)(post_w + j*64 + c8*8 + 4);
        const f32x4 pb0 = *(const f32x4*)(post_b + j*64 + c8*8);
        const f32x4 pb1 = *(const f32x4*)(post_b + j*64 + c8*8 + 4);
        float g[8];
        #pragma unroll
        for (int i = 0; i < 8; ++i) {
          const float v = (float)f[c8][i];
          const float w = i < 4 ? pw0[i] : pw1[i-4];
          const float b = i < 4 ? pb0[i] : pb1[i-4];
          g[i] = gelu_f((v-mu)*rs*w + b);
        }
        u32x4v pk = { cvtpk(g[0],g[1]), cvtpk(g[2],g[3]), cvtpk(g[4],g[5]), cvtpk(g[6],g[7]) };
        *(u32x4v*)(smem + RG_AT(RGB(j), px, c8*16)) = pk;
      }
    }
  }
  __syncthreads();

  // ---- proj GEMM: D[o][px], K=1024 (attn half from regions) ----
  f32x4 pacc[2][4];
  #pragma unroll
  for (int mt = 0; mt < 2; ++mt)
    #pragma unroll
    for (int nt = 0; nt < 4; ++nt) pacc[mt][nt] = ZERO4;
  for (int j8 = 0; j8 < 8; ++j8) {
    #pragma unroll
    for (int kt2 = 0; kt2 < 2; ++kt2) {
      bf16x8 b[4];
      #pragma unroll
      for (int nt = 0; nt < 4; ++nt) {
        const int row = nt*16 + l16, rc = row < 49 ? row : 48;
        b[nt] = *(const bf16x8*)(smem + RG_AT(RGB(j8), rc, (kt2*32 + lk*8)*2));
      }
      const int kg = j8*64 + kt2*32 + lk*8;
      #pragma unroll
      for (int mt = 0; mt < 2; ++mt) {
        const bf16x8 aw = *(const bf16x8*)(wsc + PJW_OFF + (size_t)(wv*32 + mt*16 + l16)*2048 + kg*2);
        PRIO(1);
        #pragma unroll
        for (int nt = 0; nt < 4; ++nt) pacc[mt][nt] = MFMA(aw, b[nt], pacc[mt][nt]);
        PRIO(0);
      }
    }
  }
  // idle half: 2 chunks of 256 ch through scratch overlay [64 px][256 c]
  for (int half = 0; half < 2; ++half) {
    __syncthreads();
    f32x4 ia[2][4];
    #pragma unroll
    for (int mt = 0; mt < 2; ++mt)
      #pragma unroll
      for (int nt = 0; nt < 4; ++nt) ia[mt][nt] = ZERO4;
    const int r0 = 512 + half*256 + wv*32;
    #pragma unroll 2
    for (int kt = 0; kt < 8; ++kt) {
      bf16x8 b[4];
      #pragma unroll
      for (int nt = 0; nt < 4; ++nt) {
        const int row = nt*16 + l16, rc = row < 49 ? row : 48;
        b[nt] = *(const bf16x8*)(smem + SXN_AT(rc, kt*64 + lk*16));
      }
      #pragma unroll
      for (int mt = 0; mt < 2; ++mt) {
        const bf16x8 aw = *(const bf16x8*)(wsc + VW_OFF + (size_t)(r0 + mt*16 + l16)*512 + kt*64 + lk*16);
        PRIO(1);
        #pragma unroll
        for (int nt = 0; nt < 4; ++nt) ia[mt][nt] = MFMA(aw, b[nt], ia[mt][nt]);
        PRIO(0);
      }
    }
    #pragma unroll
    for (int mt = 0; mt < 2; ++mt) {
      const f32x4 vb = *(const f32x4*)(v_b + r0 + mt*16 + lk*4);
      #pragma unroll
      for (int nt = 0; nt < 4; ++nt) {
        const int px = nt*16 + l16;
        const int chl = wv*32 + mt*16 + lk*4;
        u32x2 pk = { cvtpk(gelu_f(ia[mt][nt][0]+vb[0]), gelu_f(ia[mt][nt][1]+vb[1])),
                     cvtpk(gelu_f(ia[mt][nt][2]+vb[2]), gelu_f(ia[mt][nt][3]+vb[3])) };
        *(u32x2*)(smem + SC_AT(px, chl*2)) = pk;
      }
    }
    __syncthreads();
    #pragma unroll 2
    for (int kt = 0; kt < 8; ++kt) {
      bf16x8 b[4];
      #pragma unroll
      for (int nt = 0; nt < 4; ++nt) {
        const int row = nt*16 + l16;
        b[nt] = *(const bf16x8*)(smem + SC_AT(row, (kt*32 + lk*8)*2));
      }
      const int kg = 512 + half*256 + kt*32 + lk*8;
      #pragma unroll
      for (int mt = 0; mt < 2; ++mt) {
        const bf16x8 aw = *(const bf16x8*)(wsc + PJW_OFF + (size_t)(wv*32 + mt*16 + l16)*2048 + kg*2);
        PRIO(1);
        #pragma unroll
        for (int nt = 0; nt < 4; ++nt) pacc[mt][nt] = MFMA(aw, b[nt], pacc[mt][nt]);
        PRIO(0);
      }
    }
  }

  // ---- epilogue: + proj_b + residual, roll(+2,+2) store (R0 fused form) ----
  {
    int xoff[4], roff[4];
    #pragma unroll
    for (int nt = 0; nt < 4; ++nt) {
      const int px = nt*16 + l16;
      const int pc = px < 49 ? px : 48;
      const int gh = (pc/7)*4 + n1, gw = (pc%7)*4 + n2;
      xoff[nt] = gh*28 + gw;
      int rh = gh + 2; if (rh >= 28) rh -= 28;
      int rw = gw + 2; if (rw >= 28) rw -= 28;
      roff[nt] = rh*28 + rw;
    }
    #pragma unroll
    for (int mt = 0; mt < 2; ++mt) {
      #pragma unroll
      for (int r = 0; r < 4; ++r) {
        const int o2 = wv*32 + mt*16 + lk*4 + r;
        const float pb = proj_b[o2];
        const size_t cb = xbase + (size_t)o2*784;
        #pragma unroll
        for (int nt = 0; nt < 4; ++nt) {
          if (nt*16 + l16 < 49)
            out[cb + roff[nt]] = x[cb + xoff[nt]] + pacc[mt][nt][r] + pb;
        }
      }
    }
  }
}

extern "C" void kernel_launch(void* const* d_in, const int* in_sizes, int n_in,
                              void* d_out, int out_size, void* d_ws, size_t ws_size,
                              hipStream_t stream) {
  const float* x      = (const float*)d_in[0];
  const float* pre_w  = (const float*)d_in[1];
  const float* pre_b  = (const float*)d_in[2];
  const float* qk_w   = (const float*)d_in[3];
  const float* qk_b   = (const float*)d_in[4];
  const float* v_w    = (const float*)d_in[5];
  const float* v_b    = (const float*)d_in[6];
  const float* post_w = (const float*)d_in[7];
  const float* post_b = (const float*)d_in[8];
  const float* proj_w = (const float*)d_in[9];
  const float* proj_b = (const float*)d_in[10];
  const float* rpb    = (const float*)d_in[11];
  float* outp = (float*)d_out;
  char* wsc = (char*)d_ws;

  hipFuncSetAttribute((const void*)emo_main, hipFuncAttributeMaxDynamicSharedMemorySize, 81920);

  emo_prep<<<4288, 256, 0, stream>>>(x, pre_w, pre_b, qk_w, v_w, proj_w, rpb,
                                     (unsigned short*)(wsc + XT_OFF),
                                     (unsigned short*)wsc, (float*)(wsc + BIAS_OFF));
  emo_main<<<1024, 512, 76288, stream>>>(x, qk_b, v_b, post_w, post_b, proj_b,
                                         (const char*)wsc, outp);
}

// Round 12
// 281.628 us; speedup vs baseline: 1.2528x; 1.0077x over previous
//
#include <hip/hip_runtime.h>
#include <hip/hip_bf16.h>

typedef __bf16          bf16x8 __attribute__((ext_vector_type(8)));
typedef float           f32x4  __attribute__((ext_vector_type(4)));
typedef unsigned int    u32x2  __attribute__((ext_vector_type(2)));
typedef unsigned int    u32x4v __attribute__((ext_vector_type(4)));

// d_ws layout (bytes)
#define QKW_OFF  0           // 512*256 bf16                        (262144)
#define VW_OFF   262144      // 1024*256 bf16                       (524288)
#define PJW_OFF  786432      // 256*1024 bf16                       (524288)
#define BIAS_OFF 1310720     // [16 win][8 h][16 chunk][64 lane][4 r] f32 (2097152)
#define XT_OFF   70516736    // [64 b][16 win][49 px][256 c] bf16   (25690112)

#define MFMA(a,b,c) __builtin_amdgcn_mfma_f32_16x16x32_bf16((a),(b),(c),0,0,0)
#define ZERO4 ((f32x4){0.f,0.f,0.f,0.f})
#define CBAR() asm volatile("" ::: "memory")
#define PRIO(n) __builtin_amdgcn_s_setprio(n)

// LDS map (76288 B):
//   [0, 25088)        sXN [49 px][256 c] bf16, row 512 B, swz ^((row&7)<<4)
//   [25088, 76288)    8 regions of 6400 B (50*128, 128-aligned bases):
//                     per-wave scratch during attention (q/k -> P -> va),
//                     then out[49 q][64 ch] row 128 B; also idle-v scratch.
// STRUCTURE NOTE (R8/R9 lessons): this kernel sits on a register-allocation
// cliff at the 128 reg/wave budget (launch_bounds(512,4) x 2 blocks/CU).
// Restructuring the post-attention phases (idle-v merge, wider accumulators,
// full unroll) tips it into scratch spills (+70..+220 MB WRITE). Do not widen
// any accumulator live range; SC-overlay idle-v structure is load-bearing.
// Block mapping must stay batch-grouped (R6: win-pinned swizzle breaks the
// fused epilogue's L2 write-merging of interleaved window lines).
#define SXN_AT(row, byte)      ((((row)*512 + (byte))) ^ ((((row)&7))<<4))
#define RGB(j)                 (25088 + (j)*6400)
#define RG_AT(base, row, byte) (((base) + (row)*128 + (byte)) ^ (((row)&7)<<4))
#define SC_AT(row, byte)       ((25088 + (row)*512 + (byte)) ^ (((row)&7)<<4))

static __device__ __forceinline__ unsigned cvtpk(float lo, float hi){
  unsigned r;
  asm("v_cvt_pk_bf16_f32 %0, %1, %2" : "=v"(r) : "v"(lo), "v"(hi));
  return r;
}
static __device__ __forceinline__ unsigned short f2bu(float f) {
  unsigned u = __builtin_bit_cast(unsigned, f);
  return (unsigned short)((u + 0x7FFFu + ((u >> 16) & 1u)) >> 16);
}
static __device__ __forceinline__ float gelu_f(float v){
  // v * sigmoid(1.5957691*v*(1+0.044715 v^2)) == tanh-form gelu, |err| < ~1e-3
  return v / (1.f + __expf(-1.5957691216057308f*v*(1.f + 0.044715f*v*v)));
}

// ---------------- prep (single launch): pre-LN/window transform + weights + bias ----------------
// blocks [0,1600): pre-LN + NCHW->xt window transform (chunk = blk%25, b = blk/25)
// blocks [1600,2240): weight fp32->bf16 convert, f32x4 vectorized (4 elems/thread)
// blocks [2240,2368): bias table build
__global__ __launch_bounds__(256)
void emo_prep(const float* __restrict__ x, const float* __restrict__ pre_w,
              const float* __restrict__ pre_b,
              const float* __restrict__ qk_w, const float* __restrict__ v_w,
              const float* __restrict__ proj_w, const float* __restrict__ rpb,
              unsigned short* __restrict__ xt,
              unsigned short* __restrict__ w16, float* __restrict__ bx) {
  const int blk = blockIdx.x;
  const int tid = threadIdx.x;
  if (blk >= 1600) {
    if (blk < 2240) {          // ---- weight convert (vectorized; boundaries 4-aligned) ----
      const int i = (blk - 1600) * 1024 + tid * 4;
      if (i >= 655360) return;
      f32x4 v;
      if (i < 131072)      v = *(const f32x4*)(qk_w + i);
      else if (i < 393216) v = *(const f32x4*)(v_w + (i - 131072));
      else                 v = *(const f32x4*)(proj_w + (i - 393216));
      u32x2 pk = { cvtpk(v[0], v[1]), cvtpk(v[2], v[3]) };
      *(u32x2*)(w16 + i) = pk;
    } else {                   // ---- bias table ----
      const int wh = blk - 2240;          // win*8 + h
      const int win = wh >> 3, h = wh & 7;
      for (int e = tid; e < 4096; e += 256) {
        const int chunk = e >> 8, lane = (e >> 2) & 63, r = e & 3;
        const int mt = chunk >> 2, nt = chunk & 3;
        const int m = mt*16 + (lane >> 4)*4 + r;   // query pixel
        const int n = nt*16 + (lane & 15);         // key pixel
        float v;
        if (n >= 49)      v = -1e30f;              // softmax mask over key dim
        else if (m >= 49) v = 0.f;
        else {
          const int dI = m/7 - n/7 + 6;
          const int dJ = m%7 - n%7 + 6;
          v = rpb[(win*169 + dI*13 + dJ)*8 + h];
        }
        bx[wh*4096 + e] = v;
      }
    }
    return;
  }
  // ---- pre-LN + window transform ----
  __shared__ float lv[32*257];     // 32896 B
  __shared__ float ps1[8][32];
  __shared__ float ps2[8][32];
  const int lane = tid & 63, wv = tid >> 6;
  const int l32 = lane & 31, hp = lane >> 5;
  const int chunk = blk % 25, b = blk / 25;
  const int s = chunk*32 + l32;            // spatial index h*28+w
  const bool ok = s < 784;
  const float* xb = x + (size_t)b*200704;  // 256*784
  float s1 = 0.f, s2 = 0.f;
  const int c0 = wv*64 + hp*32;
  for (int ci = 0; ci < 32; ++ci) {
    const int c = c0 + ci;
    const float v = ok ? xb[c*784 + s] : 0.f;
    lv[l32*257 + c] = v;
    s1 += v; s2 += v*v;
  }
  ps1[wv*2 + hp][l32] = s1;
  ps2[wv*2 + hp][l32] = s2;
  __syncthreads();
  const int px = tid & 31, j = tid >> 5;
  const int sp = chunk*32 + px;
  if (sp < 784) {
    float t1 = 0.f, t2 = 0.f;
    #pragma unroll
    for (int k = 0; k < 8; ++k) { t1 += ps1[k][px]; t2 += ps2[k][px]; }
    const float mu = t1*(1.f/256.f);
    const float rs = rsqrtf(t2*(1.f/256.f) - mu*mu + 1e-5f);
    const int h = sp/28, w = sp - h*28;
    const int win = (h & 3)*4 + (w & 3);         // n1*4 + n2
    const int wpx = (h >> 2)*7 + (w >> 2);       // ph*7 + pw
    unsigned short* row = xt + (((size_t)b*16 + win)*49 + wpx)*256 + j*32;
    #pragma unroll
    for (int g = 0; g < 4; ++g) {
      float gg[8];
      #pragma unroll
      for (int i2 = 0; i2 < 8; ++i2) {
        const int c = j*32 + g*8 + i2;
        gg[i2] = (lv[px*257 + c] - mu)*rs*pre_w[c] + pre_b[c];
      }
      u32x4v pk = { cvtpk(gg[0],gg[1]), cvtpk(gg[2],gg[3]), cvtpk(gg[4],gg[5]), cvtpk(gg[6],gg[7]) };
      *(u32x4v*)(row + g*8) = pk;
    }
  }
}

// ---------------- main fused kernel (R11 structure = verified best, 283.8 us total) ----------------
// Change vs R11 (codegen-local, spill-checked via WRITE_SIZE): #pragma unroll 2 on the
// attn-proj j8 loop — per-iter live set (b[4]+aw ~20 regs) x2 + pacc(32) ~ 80 regs,
// under the va loop's working 128; doubles loads-in-flight in a 16-iter L2-bound phase.
__global__ __launch_bounds__(512, 4)
void emo_main(const float* __restrict__ x,
              const float* __restrict__ qk_b,  const float* __restrict__ v_b,
              const float* __restrict__ post_w,const float* __restrict__ post_b,
              const float* __restrict__ proj_b,
              const char*  __restrict__ wsc,
              float* __restrict__ out)
{
  extern __shared__ char smem[];
  const int tid  = threadIdx.x;
  const int lane = tid & 63;
  const int l16  = lane & 15;
  const int lk   = lane >> 4;
  const int wv   = tid >> 6;                 // wave = head
  const int bid  = blockIdx.x;
  const int Bi   = (bid & 7) * 8 + (bid >> 7);   // XCD swizzle (bijective, R0 form)
  const int win  = (bid >> 3) & 15;
  const int n1   = win >> 2, n2 = win & 3;
  const size_t xbase = (size_t)Bi * (256*784);
  const int SCR  = RGB(wv);                  // per-wave scratch base

  // ---- prefetch qk weights for kt=0 (LDS-independent; hides latency under stage A) ----
  bf16x8 awq0[2], awk0[2];
  #pragma unroll
  for (int mt = 0; mt < 2; ++mt) {
    awq0[mt] = *(const bf16x8*)(wsc + QKW_OFF + (size_t)(      wv*32 + mt*16 + l16)*512 + lk*16);
    awk0[mt] = *(const bf16x8*)(wsc + QKW_OFF + (size_t)(256 + wv*32 + mt*16 + l16)*512 + lk*16);
  }

  // ---- stage A: coalesced copy xt[b][win][px][c] -> sXN (swizzled) ----
  {
    const unsigned short* xw = (const unsigned short*)(wsc + XT_OFF)
                             + ((size_t)Bi*16 + win)*(49*256);
    for (int p = wv; p < 49; p += 8) {
      const u32x2 d = *(const u32x2*)(xw + p*256 + lane*4);
      *(u32x2*)(smem + SXN_AT(p, lane*8)) = d;
    }
  }
  __syncthreads();

  // ---- qk GEMM: aq/ak = D[d][px] C-frags (kt=0 peeled with prefetched weights) ----
  f32x4 aq[2][4], ak[2][4];
  {
    bf16x8 bx[4];
    #pragma unroll
    for (int nt = 0; nt < 4; ++nt) {
      const int row = nt*16 + l16, rc = row < 49 ? row : 48;
      bx[nt] = *(const bf16x8*)(smem + SXN_AT(rc, lk*16));
    }
    PRIO(1);
    #pragma unroll
    for (int mt = 0; mt < 2; ++mt)
      #pragma unroll
      for (int nt = 0; nt < 4; ++nt) {
        aq[mt][nt] = MFMA(awq0[mt], bx[nt], ZERO4);
        ak[mt][nt] = MFMA(awk0[mt], bx[nt], ZERO4);
      }
    PRIO(0);
  }
  #pragma unroll 2
  for (int kt = 1; kt < 8; ++kt) {
    bf16x8 bx[4];
    #pragma unroll
    for (int nt = 0; nt < 4; ++nt) {
      const int row = nt*16 + l16, rc = row < 49 ? row : 48;
      bx[nt] = *(const bf16x8*)(smem + SXN_AT(rc, kt*64 + lk*16));
    }
    #pragma unroll
    for (int mt = 0; mt < 2; ++mt) {
      const bf16x8 awq = *(const bf16x8*)(wsc + QKW_OFF + (size_t)(      wv*32 + mt*16 + l16)*512 + kt*64 + lk*16);
      const bf16x8 awk = *(const bf16x8*)(wsc + QKW_OFF + (size_t)(256 + wv*32 + mt*16 + l16)*512 + kt*64 + lk*16);
      PRIO(1);
      #pragma unroll
      for (int nt = 0; nt < 4; ++nt) {
        aq[mt][nt] = MFMA(awq, bx[nt], aq[mt][nt]);
        ak[mt][nt] = MFMA(awk, bx[nt], ak[mt][nt]);
      }
      PRIO(0);
    }
  }
  { // + qk bias (per d row)
    const f32x4 bq0 = *(const f32x4*)(qk_b +       wv*32 +      lk*4);
    const f32x4 bq1 = *(const f32x4*)(qk_b +       wv*32 + 16 + lk*4);
    const f32x4 bk0 = *(const f32x4*)(qk_b + 256 + wv*32 +      lk*4);
    const f32x4 bk1 = *(const f32x4*)(qk_b + 256 + wv*32 + 16 + lk*4);
    #pragma unroll
    for (int nt = 0; nt < 4; ++nt) {
      aq[0][nt] += bq0; aq[1][nt] += bq1; ak[0][nt] += bk0; ak[1][nt] += bk1;
    }
  }

  // ---- spill q/k to scratch [px][ q: bytes 0..63 | k: bytes 64..127 ], rows 0..48 ----
  #pragma unroll
  for (int nt = 0; nt < 4; ++nt) {
    const int px = nt*16 + l16;
    if (px < 49) {
      #pragma unroll
      for (int mt = 0; mt < 2; ++mt) {
        u32x2 pq  = { cvtpk(aq[mt][nt][0], aq[mt][nt][1]), cvtpk(aq[mt][nt][2], aq[mt][nt][3]) };
        u32x2 pk2 = { cvtpk(ak[mt][nt][0], ak[mt][nt][1]), cvtpk(ak[mt][nt][2], ak[mt][nt][3]) };
        *(u32x2*)(smem + RG_AT(SCR, px,      (mt*16 + lk*4)*2)) = pq;
        *(u32x2*)(smem + RG_AT(SCR, px, 64 + (mt*16 + lk*4)*2)) = pk2;
      }
    }
  }
  CBAR();

  // ---- reload q/k as A/B fragments (round-2 pinned pattern) ----
  bf16x8 qa[4], kb[4];
  #pragma unroll
  for (int t = 0; t < 4; ++t) {
    const int row = t*16 + l16, rc = row < 49 ? row : 48;
    qa[t] = *(const bf16x8*)(smem + RG_AT(SCR, rc,      lk*16));
    kb[t] = *(const bf16x8*)(smem + RG_AT(SCR, rc, 64 + lk*16));
  }

  // ---- QK^T: S[q][k] + bias (round-2 orientation) ----
  f32x4 s[4][4];
  {
    const float scale = 0.17677669529663689f;
    const float* bxp = (const float*)(wsc + BIAS_OFF) + (size_t)(win*8 + wv)*4096 + lane*4;
    PRIO(1);
    #pragma unroll
    for (int mt = 0; mt < 4; ++mt)
      #pragma unroll
      for (int nt = 0; nt < 4; ++nt) {
        f32x4 z = MFMA(qa[mt], kb[nt], ZERO4);
        s[mt][nt] = z*scale + *(const f32x4*)(bxp + (mt*4 + nt)*256);
      }
    PRIO(0);
  }
  // ---- softmax over k (nt regs + l16 lanes) for each q-row (mt, r) ----
  #pragma unroll
  for (int mt = 0; mt < 4; ++mt) {
    #pragma unroll
    for (int r = 0; r < 4; ++r) {
      float mx = fmaxf(fmaxf(s[mt][0][r], s[mt][1][r]), fmaxf(s[mt][2][r], s[mt][3][r]));
      mx = fmaxf(mx, __shfl_xor(mx, 1)); mx = fmaxf(mx, __shfl_xor(mx, 2));
      mx = fmaxf(mx, __shfl_xor(mx, 4)); mx = fmaxf(mx, __shfl_xor(mx, 8));
      const float e0 = __expf(s[mt][0][r]-mx), e1 = __expf(s[mt][1][r]-mx);
      const float e2 = __expf(s[mt][2][r]-mx), e3 = __expf(s[mt][3][r]-mx);
      float sm = e0+e1+e2+e3;
      sm += __shfl_xor(sm, 1); sm += __shfl_xor(sm, 2);
      sm += __shfl_xor(sm, 4); sm += __shfl_xor(sm, 8);
      const float inv = 1.f/sm;
      s[mt][0][r] = e0*inv; s[mt][1][r] = e1*inv;
      s[mt][2][r] = e2*inv; s[mt][3][r] = e3*inv;
    }
  }
  // ---- store P [q][k] rows 0..48 (all 64 k cols; masked cols are exactly 0) ----
  #pragma unroll
  for (int mt = 0; mt < 4; ++mt)
    #pragma unroll
    for (int r = 0; r < 4; ++r) {
      const int q = mt*16 + lk*4 + r;
      if (q < 49) {
        #pragma unroll
        for (int nt = 0; nt < 4; ++nt)
          *(unsigned short*)(smem + RG_AT(SCR, q, (nt*16 + l16)*2)) = f2bu(s[mt][nt][r]);
      }
    }
  CBAR();

  // ---- va GEMM: av = D[px][ch] C-frags ----
  f32x4 av[4][4];
  #pragma unroll
  for (int mt = 0; mt < 4; ++mt)
    #pragma unroll
    for (int nt = 0; nt < 4; ++nt) av[mt][nt] = ZERO4;
  #pragma unroll 2
  for (int kt = 0; kt < 8; ++kt) {
    bf16x8 ax[4], bw[4];
    #pragma unroll
    for (int t = 0; t < 4; ++t) {
      const int row = t*16 + l16, rc = row < 49 ? row : 48;
      ax[t] = *(const bf16x8*)(smem + SXN_AT(rc, kt*64 + lk*16));
      bw[t] = *(const bf16x8*)(wsc + VW_OFF + (size_t)(wv*64 + t*16 + l16)*512 + kt*64 + lk*16);
    }
    PRIO(1);
    #pragma unroll
    for (int mt = 0; mt < 4; ++mt)
      #pragma unroll
      for (int nt = 0; nt < 4; ++nt) av[mt][nt] = MFMA(ax[mt], bw[nt], av[mt][nt]);
    PRIO(0);
  }
  { // + v bias (per ch col)
    #pragma unroll
    for (int nt = 0; nt < 4; ++nt) {
      const float vb = v_b[wv*64 + nt*16 + l16];
      #pragma unroll
      for (int mt = 0; mt < 4; ++mt)
        #pragma unroll
        for (int r = 0; r < 4; ++r) av[mt][nt][r] += vb;
    }
  }

  // ---- read P as B-frags (round-2 pinned pattern) ----
  bf16x8 fpb[4][2];
  #pragma unroll
  for (int t = 0; t < 4; ++t) {
    const int row = t*16 + l16, rc = row < 49 ? row : 48;
    #pragma unroll
    for (int kt = 0; kt < 2; ++kt)
      fpb[t][kt] = *(const bf16x8*)(smem + RG_AT(SCR, rc, (kt*32 + lk*8)*2));
  }
  CBAR();

  // ---- PV in two 32-ch halves through scratch [ch][px] (rows 0..31) ----
  f32x4 o[4][4];
  #pragma unroll
  for (int h2 = 0; h2 < 2; ++h2) {
    #pragma unroll
    for (int tc = 0; tc < 2; ++tc) {
      const int nt = h2*2 + tc;          // global ch tile
      const int chrow = tc*16 + l16;     // row within this half
      #pragma unroll
      for (int mt = 0; mt < 4; ++mt) {
        u32x2 pv = { cvtpk(av[mt][nt][0], av[mt][nt][1]), cvtpk(av[mt][nt][2], av[mt][nt][3]) };
        *(u32x2*)(smem + RG_AT(SCR, chrow, (mt*16 + lk*4)*2)) = pv;
      }
    }
    CBAR();
    #pragma unroll
    for (int tc = 0; tc < 2; ++tc) {
      const int mtc = h2*2 + tc;
      const bf16x8 a0 = *(const bf16x8*)(smem + RG_AT(SCR, tc*16 + l16, (     lk*8)*2));
      const bf16x8 a1 = *(const bf16x8*)(smem + RG_AT(SCR, tc*16 + l16, (32 + lk*8)*2));
      PRIO(1);
      #pragma unroll
      for (int nt = 0; nt < 4; ++nt) {
        f32x4 z = MFMA(a0, fpb[nt][0], ZERO4);
        o[mtc][nt] = MFMA(a1, fpb[nt][1], z);
      }
      PRIO(0);
    }
    CBAR();
  }

  // ---- store attention out [q][ch] into region wv ----
  #pragma unroll
  for (int mtc = 0; mtc < 4; ++mtc)
    #pragma unroll
    for (int nt = 0; nt < 4; ++nt) {
      const int q = nt*16 + l16;
      if (q < 49) {
        u32x2 pk = { cvtpk(o[mtc][nt][0], o[mtc][nt][1]), cvtpk(o[mtc][nt][2], o[mtc][nt][3]) };
        *(u32x2*)(smem + RG_AT(RGB(wv), q, (mtc*16 + lk*4)*2)) = pk;
      }
    }
  __syncthreads();

  // ---- post-LN (512 ch) + gelu, in place on regions ----
  {
    const int px = tid >> 3, j = tid & 7;
    if (px < 49) {
      bf16x8 f[8];
      float s1 = 0.f, s2 = 0.f;
      #pragma unroll
      for (int c8 = 0; c8 < 8; ++c8) {
        f[c8] = *(const bf16x8*)(smem + RG_AT(RGB(j), px, c8*16));
        #pragma unroll
        for (int i = 0; i < 8; ++i) { const float v = (float)f[c8][i]; s1 += v; s2 += v*v; }
      }
      s1 += __shfl_xor(s1, 1); s1 += __shfl_xor(s1, 2); s1 += __shfl_xor(s1, 4);
      s2 += __shfl_xor(s2, 1); s2 += __shfl_xor(s2, 2); s2 += __shfl_xor(s2, 4);
      const float mu = s1*(1.f/512.f);
      const float rs = rsqrtf(s2*(1.f/512.f) - mu*mu + 1e-5f);
      #pragma unroll
      for (int c8 = 0; c8 < 8; ++c8) {
        const f32x4 pw0 = *(const f32x4*)(post_w + j*64 + c8*8);
        const f32x4 pw1 = *(const f32x4*)(post_w + j*64 + c8*8 + 4);
        const f32x4 pb0 = *(const f32x4*)(post_b + j*64 + c8*8);
        const f32x4 pb1 = *(const f32x4*)(post_b + j*64 + c8*8 + 4);
        float g[8];
        #pragma unroll
        for (int i = 0; i < 8; ++i) {
          const float v = (float)f[c8][i];
          const float w = i < 4 ? pw0[i] : pw1[i-4];
          const float b = i < 4 ? pb0[i] : pb1[i-4];
          g[i] = gelu_f((v-mu)*rs*w + b);
        }
        u32x4v pk = { cvtpk(g[0],g[1]), cvtpk(g[2],g[3]), cvtpk(g[4],g[5]), cvtpk(g[6],g[7]) };
        *(u32x4v*)(smem + RG_AT(RGB(j), px, c8*16)) = pk;
      }
    }
  }
  __syncthreads();

  // ---- proj GEMM: D[o][px], K=1024 (attn half from regions) ----
  f32x4 pacc[2][4];
  #pragma unroll
  for (int mt = 0; mt < 2; ++mt)
    #pragma unroll
    for (int nt = 0; nt < 4; ++nt) pacc[mt][nt] = ZERO4;
  #pragma unroll 2
  for (int j8 = 0; j8 < 8; ++j8) {
    #pragma unroll
    for (int kt2 = 0; kt2 < 2; ++kt2) {
      bf16x8 b[4];
      #pragma unroll
      for (int nt = 0; nt < 4; ++nt) {
        const int row = nt*16 + l16, rc = row < 49 ? row : 48;
        b[nt] = *(const bf16x8*)(smem + RG_AT(RGB(j8), rc, (kt2*32 + lk*8)*2));
      }
      const int kg = j8*64 + kt2*32 + lk*8;
      #pragma unroll
      for (int mt = 0; mt < 2; ++mt) {
        const bf16x8 aw = *(const bf16x8*)(wsc + PJW_OFF + (size_t)(wv*32 + mt*16 + l16)*2048 + kg*2);
        PRIO(1);
        #pragma unroll
        for (int nt = 0; nt < 4; ++nt) pacc[mt][nt] = MFMA(aw, b[nt], pacc[mt][nt]);
        PRIO(0);
      }
    }
  }
  // idle half: 2 chunks of 256 ch through scratch overlay [64 px][256 c]
  for (int half = 0; half < 2; ++half) {
    __syncthreads();
    f32x4 ia[2][4];
    #pragma unroll
    for (int mt = 0; mt < 2; ++mt)
      #pragma unroll
      for (int nt = 0; nt < 4; ++nt) ia[mt][nt] = ZERO4;
    const int r0 = 512 + half*256 + wv*32;
    #pragma unroll 2
    for (int kt = 0; kt < 8; ++kt) {
      bf16x8 b[4];
      #pragma unroll
      for (int nt = 0; nt < 4; ++nt) {
        const int row = nt*16 + l16, rc = row < 49 ? row : 48;
        b[nt] = *(const bf16x8*)(smem + SXN_AT(rc, kt*64 + lk*16));
      }
      #pragma unroll
      for (int mt = 0; mt < 2; ++mt) {
        const bf16x8 aw = *(const bf16x8*)(wsc + VW_OFF + (size_t)(r0 + mt*16 + l16)*512 + kt*64 + lk*16);
        PRIO(1);
        #pragma unroll
        for (int nt = 0; nt < 4; ++nt) ia[mt][nt] = MFMA(aw, b[nt], ia[mt][nt]);
        PRIO(0);
      }
    }
    #pragma unroll
    for (int mt = 0; mt < 2; ++mt) {
      const f32x4 vb = *(const f32x4*)(v_b + r0 + mt*16 + lk*4);
      #pragma unroll
      for (int nt = 0; nt < 4; ++nt) {
        const int px = nt*16 + l16;
        const int chl = wv*32 + mt*16 + lk*4;
        u32x2 pk = { cvtpk(gelu_f(ia[mt][nt][0]+vb[0]), gelu_f(ia[mt][nt][1]+vb[1])),
                     cvtpk(gelu_f(ia[mt][nt][2]+vb[2]), gelu_f(ia[mt][nt][3]+vb[3])) };
        *(u32x2*)(smem + SC_AT(px, chl*2)) = pk;
      }
    }
    __syncthreads();
    #pragma unroll 2
    for (int kt = 0; kt < 8; ++kt) {
      bf16x8 b[4];
      #pragma unroll
      for (int nt = 0; nt < 4; ++nt) {
        const int row = nt*16 + l16;
        b[nt] = *(const bf16x8*)(smem + SC_AT(row, (kt*32 + lk*8)*2));
      }
      const int kg = 512 + half*256 + kt*32 + lk*8;
      #pragma unroll
      for (int mt = 0; mt < 2; ++mt) {
        const bf16x8 aw = *(const bf16x8*)(wsc + PJW_OFF + (size_t)(wv*32 + mt*16 + l16)*2048 + kg*2);
        PRIO(1);
        #pragma unroll
        for (int nt = 0; nt < 4; ++nt) pacc[mt][nt] = MFMA(aw, b[nt], pacc[mt][nt]);
        PRIO(0);
      }
    }
  }

  // ---- epilogue: + proj_b + residual, roll(+2,+2) store (R0 fused form) ----
  {
    int xoff[4], roff[4];
    #pragma unroll
    for (int nt = 0; nt < 4; ++nt) {
      const int px = nt*16 + l16;
      const int pc = px < 49 ? px : 48;
      const int gh = (pc/7)*4 + n1, gw = (pc%7)*4 + n2;
      xoff[nt] = gh*28 + gw;
      int rh = gh + 2; if (rh >= 28) rh -= 28;
      int rw = gw + 2; if (rw >= 28) rw -= 28;
      roff[nt] = rh*28 + rw;
    }
    #pragma unroll
    for (int mt = 0; mt < 2; ++mt) {
      #pragma unroll
      for (int r = 0; r < 4; ++r) {
        const int o2 = wv*32 + mt*16 + lk*4 + r;
        const float pb = proj_b[o2];
        const size_t cb = xbase + (size_t)o2*784;
        #pragma unroll
        for (int nt = 0; nt < 4; ++nt) {
          if (nt*16 + l16 < 49)
            out[cb + roff[nt]] = x[cb + xoff[nt]] + pacc[mt][nt][r] + pb;
        }
      }
    }
  }
}

extern "C" void kernel_launch(void* const* d_in, const int* in_sizes, int n_in,
                              void* d_out, int out_size, void* d_ws, size_t ws_size,
                              hipStream_t stream) {
  const float* x      = (const float*)d_in[0];
  const float* pre_w  = (const float*)d_in[1];
  const float* pre_b  = (const float*)d_in[2];
  const float* qk_w   = (const float*)d_in[3];
  const float* qk_b   = (const float*)d_in[4];
  const float* v_w    = (const float*)d_in[5];
  const float* v_b    = (const float*)d_in[6];
  const float* post_w = (const float*)d_in[7];
  const float* post_b = (const float*)d_in[8];
  const float* proj_w = (const float*)d_in[9];
  const float* proj_b = (const float*)d_in[10];
  const float* rpb    = (const float*)d_in[11];
  float* outp = (float*)d_out;
  char* wsc = (char*)d_ws;

  hipFuncSetAttribute((const void*)emo_main, hipFuncAttributeMaxDynamicSharedMemorySize, 81920);

  emo_prep<<<2368, 256, 0, stream>>>(x, pre_w, pre_b, qk_w, v_w, proj_w, rpb,
                                     (unsigned short*)(wsc + XT_OFF),
                                     (unsigned short*)wsc, (float*)(wsc + BIAS_OFF));
  emo_main<<<1024, 512, 76288, stream>>>(x, qk_b, v_b, post_w, post_b, proj_b,
                                         (const char*)wsc, outp);
}